// Round 1
// baseline (12561.540 us; speedup 1.0000x reference)
//
#include <hip/hip_runtime.h>
#include <math.h>

#define B_ 512
#define T_ 24
#define TM1 23
#define D_ 1024
#define D3 3072
#define OUT_ 325
#define HORIZON_ 12
#define TSLOTS_ 288

// ---------------- fp32 NT GEMM: C[m,n] = sum_k A[m*lda+k]*W[n*K+k] + bias[n]
// BM=BN=64, BK=16, 256 threads, 4x4 per thread. M,N,K assumed multiples of tile.
__global__ __launch_bounds__(256) void gemm_nt_bias(
    const float* __restrict__ A, int lda,
    const float* __restrict__ W, // N x K row-major
    const float* __restrict__ bias,
    float* __restrict__ C, int ldc, int K)
{
  __shared__ float As[16][68];
  __shared__ float Bs[16][68];
  int tid = threadIdx.x;
  int bm = blockIdx.x * 64;
  int bn = blockIdx.y * 64;
  int tx = tid & 15, ty = tid >> 4;
  float acc[4][4] = {};
  int lr = tid >> 2;        // row within tile 0..63
  int lk = (tid & 3) * 4;   // k offset 0,4,8,12
  for (int k0 = 0; k0 < K; k0 += 16) {
    {
      const float* p = A + (size_t)(bm + lr) * lda + k0 + lk;
      float4 v = *(const float4*)p;
      As[lk+0][lr] = v.x; As[lk+1][lr] = v.y; As[lk+2][lr] = v.z; As[lk+3][lr] = v.w;
      const float* q = W + (size_t)(bn + lr) * K + k0 + lk;
      float4 w = *(const float4*)q;
      Bs[lk+0][lr] = w.x; Bs[lk+1][lr] = w.y; Bs[lk+2][lr] = w.z; Bs[lk+3][lr] = w.w;
    }
    __syncthreads();
    #pragma unroll
    for (int kk = 0; kk < 16; ++kk) {
      float a[4], b[4];
      *(float4*)a = *(const float4*)&As[kk][ty*4];
      *(float4*)b = *(const float4*)&Bs[kk][tx*4];
      #pragma unroll
      for (int i = 0; i < 4; ++i)
        #pragma unroll
        for (int j = 0; j < 4; ++j)
          acc[i][j] = fmaf(a[i], b[j], acc[i][j]);
    }
    __syncthreads();
  }
  #pragma unroll
  for (int i = 0; i < 4; ++i) {
    int m = bm + ty*4 + i;
    #pragma unroll
    for (int j = 0; j < 4; ++j) {
      int n = bn + tx*4 + j;
      C[(size_t)m*ldc + n] = acc[i][j] + bias[n];
    }
  }
}

// ---------------- GRU pointwise gate
// r = sig(gx_r+gh_r); z = sig(gx_z+gh_z); n = tanh(gx_n + r*gh_n)
// h' = (1-z)*n + z*h ; optionally also write h' into a sequence slot.
__global__ __launch_bounds__(256) void gru_gate(
    const float* __restrict__ GX, const float* __restrict__ GH,
    float* __restrict__ H, float* __restrict__ seq_out, int seq_pitch)
{
  int idx = blockIdx.x * 256 + threadIdx.x; // over B_*D_
  int b = idx >> 10, d = idx & 1023;
  const float* gx = GX + (size_t)b * D3;
  const float* gh = GH + (size_t)b * D3;
  float xr = gx[d],       hr = gh[d];
  float xz = gx[D_ + d],  hz = gh[D_ + d];
  float xn = gx[2*D_ + d], hn = gh[2*D_ + d];
  float r = 1.f / (1.f + expf(-(xr + hr)));
  float z = 1.f / (1.f + expf(-(xz + hz)));
  float n = tanhf(xn + r * hn);
  float h = H[(size_t)b*D_ + d];
  float hnew = (1.f - z) * n + z * h;
  H[(size_t)b*D_ + d] = hnew;
  if (seq_out) seq_out[(size_t)b*seq_pitch + d] = hnew;
}

// ---------------- embed: X[m,:] = A_row @ w_data + b_data + time_table[t%288] + day_table[wd]
// mode 0: encoder, m = b*23+t over B*23 rows, A = data(B,T,OUT), t from time[b,t]
// mode 1: decoder, m = b over B rows,          A = data_cur(B,OUT), t = time[b,T-1]+step
__global__ __launch_bounds__(256) void embed_kernel(
    const float* __restrict__ Adata,
    const int* __restrict__ timev, const int* __restrict__ weekday,
    const float* __restrict__ w_data, const float* __restrict__ b_data,
    const float* __restrict__ time_table, const float* __restrict__ day_table,
    float* __restrict__ Xout, int mode, int step)
{
  __shared__ float s_a[8][OUT_];
  __shared__ int s_ab[8], s_ti[8], s_di[8];
  int tid = threadIdx.x;
  int row0 = blockIdx.x * 8;
  if (tid < 8) {
    int m = row0 + tid;
    int abase, ti, di;
    if (mode == 0) {
      int b = m / TM1, t = m - b * TM1;
      abase = (b * T_ + t) * OUT_;
      int tv = timev[b * T_ + t];
      ti = ((tv % TSLOTS_) + TSLOTS_) % TSLOTS_;
      di = weekday[b];
    } else {
      abase = m * OUT_;
      int tv = timev[m * T_ + (T_ - 1)] + step;
      ti = ((tv % TSLOTS_) + TSLOTS_) % TSLOTS_;
      di = weekday[m];
    }
    s_ab[tid] = abase; s_ti[tid] = ti; s_di[tid] = di;
  }
  __syncthreads();
  for (int idx = tid; idx < 8 * OUT_; idx += 256) {
    int r = idx / OUT_, k = idx - r * OUT_;
    s_a[r][k] = Adata[(size_t)s_ab[r] + k];
  }
  __syncthreads();
  float acc[8][4] = {};
  for (int k = 0; k < OUT_; ++k) {
    const float* wr = w_data + (size_t)k * D_;
    float w0 = wr[tid], w1 = wr[tid+256], w2 = wr[tid+512], w3 = wr[tid+768];
    #pragma unroll
    for (int r = 0; r < 8; ++r) {
      float a = s_a[r][k];
      acc[r][0] = fmaf(a, w0, acc[r][0]);
      acc[r][1] = fmaf(a, w1, acc[r][1]);
      acc[r][2] = fmaf(a, w2, acc[r][2]);
      acc[r][3] = fmaf(a, w3, acc[r][3]);
    }
  }
  #pragma unroll
  for (int r = 0; r < 8; ++r) {
    float* o = Xout + (size_t)(row0 + r) * D_;
    const float* tt = time_table + (size_t)s_ti[r] * D_;
    const float* dt = day_table + (size_t)s_di[r] * D_;
    #pragma unroll
    for (int c = 0; c < 4; ++c) {
      int n = tid + c * 256;
      o[n] = acc[r][c] + b_data[n] + tt[n] + dt[n];
    }
  }
}

// ---------------- MLP head + feedback: res = H1 @ w_mlp + b_mlp; out = data_cur + res
__global__ __launch_bounds__(256) void mlp_out_kernel(
    const float* __restrict__ H1, const float* __restrict__ w_mlp, // (D, OUT)
    const float* __restrict__ b_mlp,
    float* __restrict__ data_cur, float* __restrict__ dout, int step)
{
  __shared__ float s_h[8][D_]; // 32 KB
  int tid = threadIdx.x;
  int row0 = blockIdx.x * 8;
  for (int idx = tid; idx < 8 * D_; idx += 256) {
    int r = idx >> 10, k = idx & 1023;
    s_h[r][k] = H1[(size_t)(row0 + r) * D_ + k];
  }
  __syncthreads();
  for (int c = 0; c < 2; ++c) {
    int j = tid + c * 256;
    if (j >= OUT_) break;
    float acc[8] = {};
    for (int k = 0; k < D_; ++k) {
      float w = w_mlp[(size_t)k * OUT_ + j];
      #pragma unroll
      for (int r = 0; r < 8; ++r) acc[r] = fmaf(s_h[r][k], w, acc[r]);
    }
    float bj = b_mlp[j];
    for (int r = 0; r < 8; ++r) {
      int b = row0 + r;
      float v = data_cur[(size_t)b * OUT_ + j] + acc[r] + bj;
      dout[((size_t)b * HORIZON_ + step) * OUT_ + j] = v;
      data_cur[(size_t)b * OUT_ + j] = v;
    }
  }
}

__global__ void init_data_cur(const float* __restrict__ data, float* __restrict__ data_cur)
{
  int idx = blockIdx.x * 256 + threadIdx.x;
  if (idx < B_ * OUT_) {
    int b = idx / OUT_, j = idx - b * OUT_;
    data_cur[idx] = data[((size_t)b * T_ + (T_ - 1)) * OUT_ + j];
  }
}

extern "C" void kernel_launch(void* const* d_in, const int* in_sizes, int n_in,
                              void* d_out, int out_size, void* d_ws, size_t ws_size,
                              hipStream_t stream) {
  const float* data       = (const float*)d_in[0];
  const int*   timev      = (const int*)  d_in[1];
  const int*   weekday    = (const int*)  d_in[2];
  const float* w_data     = (const float*)d_in[3];
  const float* b_data     = (const float*)d_in[4];
  const float* time_table = (const float*)d_in[5];
  const float* day_table  = (const float*)d_in[6];
  const float* enc_Wih    = (const float*)d_in[7];
  const float* enc_Whh    = (const float*)d_in[8];
  const float* enc_bih    = (const float*)d_in[9];
  const float* enc_bhh    = (const float*)d_in[10];
  const float* dec_Wih    = (const float*)d_in[11];
  const float* dec_Whh    = (const float*)d_in[12];
  const float* dec_bih    = (const float*)d_in[13];
  const float* dec_bhh    = (const float*)d_in[14];
  const float* w_mlp      = (const float*)d_in[15];
  const float* b_mlp      = (const float*)d_in[16];
  float* out = (float*)d_out;

  // workspace layout (floats)
  float* ws = (float*)d_ws;
  size_t off = 0;
  float* X   = ws + off; off += (size_t)B_ * TM1 * D_;   // 12,058,624
  float* GX  = ws + off; off += (size_t)B_ * D3;         // 1,572,864
  float* GH  = ws + off; off += (size_t)B_ * D3;
  float* H0  = ws + off; off += (size_t)B_ * D_;
  float* H1  = ws + off; off += (size_t)B_ * D_;
  float* XI  = ws + off; off += (size_t)B_ * D_;
  float* DC  = ws + off; off += (size_t)B_ * OUT_;
  if (ws_size < off * sizeof(float)) return; // workspace too small -> fail loudly

  dim3 gemm_grid(B_ / 64, D3 / 64);
  dim3 gemm_blk(256);
  int gate_blocks = (B_ * D_) / 256;

  // ---- encoder embed: X = embed(data[:, :23])
  embed_kernel<<<(B_ * TM1) / 8, 256, 0, stream>>>(
      data, timev, weekday, w_data, b_data, time_table, day_table, X, 0, 0);

  // ---- encoder layers
  float* Hl[2] = {H0, H1};
  for (int l = 0; l < 2; ++l) {
    hipMemsetAsync(Hl[l], 0, (size_t)B_ * D_ * sizeof(float), stream);
    const float* Wih = enc_Wih + (size_t)l * D3 * D_;
    const float* Whh = enc_Whh + (size_t)l * D3 * D_;
    const float* bih = enc_bih + (size_t)l * D3;
    const float* bhh = enc_bhh + (size_t)l * D3;
    for (int t = 0; t < TM1; ++t) {
      const float* xrow = X + (size_t)t * D_;  // row pitch TM1*D_
      gemm_nt_bias<<<gemm_grid, gemm_blk, 0, stream>>>(xrow, TM1 * D_, Wih, bih, GX, D3, D_);
      gemm_nt_bias<<<gemm_grid, gemm_blk, 0, stream>>>(Hl[l], D_, Whh, bhh, GH, D3, D_);
      // write layer output in place into X[:, t, :] (input for next layer)
      gru_gate<<<gate_blocks, 256, 0, stream>>>(GX, GH, Hl[l], X + (size_t)t * D_, TM1 * D_);
    }
  }

  // ---- decoder
  init_data_cur<<<(B_ * OUT_ + 255) / 256, 256, 0, stream>>>(data, DC);
  for (int s = 0; s < HORIZON_; ++s) {
    embed_kernel<<<B_ / 8, 256, 0, stream>>>(
        DC, timev, weekday, w_data, b_data, time_table, day_table, XI, 1, s);
    // layer 0: input XI, state H0
    gemm_nt_bias<<<gemm_grid, gemm_blk, 0, stream>>>(XI, D_, dec_Wih, dec_bih, GX, D3, D_);
    gemm_nt_bias<<<gemm_grid, gemm_blk, 0, stream>>>(H0, D_, dec_Whh, dec_bhh, GH, D3, D_);
    gru_gate<<<gate_blocks, 256, 0, stream>>>(GX, GH, H0, (float*)nullptr, 0);
    // layer 1: input H0, state H1
    gemm_nt_bias<<<gemm_grid, gemm_blk, 0, stream>>>(
        H0, D_, dec_Wih + (size_t)D3 * D_, dec_bih + D3, GX, D3, D_);
    gemm_nt_bias<<<gemm_grid, gemm_blk, 0, stream>>>(
        H1, D_, dec_Whh + (size_t)D3 * D_, dec_bhh + D3, GH, D3, D_);
    gru_gate<<<gate_blocks, 256, 0, stream>>>(GX, GH, H1, (float*)nullptr, 0);
    // head + feedback
    mlp_out_kernel<<<B_ / 8, 256, 0, stream>>>(H1, w_mlp, b_mlp, DC, out, s);
  }
}

// Round 2
// 2132.031 us; speedup vs baseline: 5.8918x; 5.8918x over previous
//
#include <hip/hip_runtime.h>
#include <math.h>

#define B_ 512
#define T_ 24
#define TM1 23
#define D_ 1024
#define OUT_ 325
#define HORIZON_ 12

typedef __attribute__((ext_vector_type(8))) short bf16x8;
typedef __attribute__((ext_vector_type(4))) float f32x4;

#define MFMA16(a, b, c) __builtin_amdgcn_mfma_f32_16x16x32_bf16((a), (b), (c), 0, 0, 0)

__device__ __forceinline__ unsigned short f2b(float f) {
  union { float f; unsigned u; } v; v.f = f;
  unsigned r = (v.u + 0x7fffu + ((v.u >> 16) & 1u)) >> 16;
  return (unsigned short)r;
}

// Packed fragment layout for an (M x K) bf16 matrix, M%64==0, K%32==0.
// Segment (m_blk, k_blk, st) is 512 contiguous elems = one wave-load (1KB):
// lane l, elem j  <->  row m_blk*64+st*16+(l&15), col k_blk*32+(l>>4)*8+j
__device__ __forceinline__ size_t pidx(int m, int k, int K) {
  return ((((size_t)(m >> 6) * (K >> 5) + (k >> 5)) * 4 + ((m >> 4) & 3)) * 64
          + ((m & 15) + (((k >> 3) & 3) << 4))) * 8 + (k & 7);
}

#define GLOAD16(src, dst) \
  __builtin_amdgcn_global_load_lds((const __attribute__((address_space(1))) void*)(src), \
                                   (__attribute__((address_space(3))) void*)(dst), 16, 0, 0)

// ================= fused GRU cell =================
// h' for tile (64 rows x 32 d-cols). Computes gx = x@Wih^T, gh = h@Whh^T for
// 3 gates via MFMA, then full gate epilogue. All operands packed bf16.
// Grid (512/64, 1024/32) = (8,32); 256 threads = 4 waves (2x2), wave = 32x16.
template<int WRITE_SEQ>
__global__ __launch_bounds__(256) void gru_cell(
    const unsigned short* __restrict__ Xp,   // packed 512x1024 (gx input)
    const unsigned short* __restrict__ Hp,   // packed 512x1024 (h input)
    const float* __restrict__ Hf,            // fp32 512x1024 (h input)
    const unsigned short* __restrict__ Wih,  // packed Nx1024 (N=6144, layer via n_base)
    const unsigned short* __restrict__ Whh,
    int n_base,
    const float* __restrict__ bih, const float* __restrict__ bhh, // layer-offset applied
    float* __restrict__ Hf_out, unsigned short* __restrict__ Hp_out,
    unsigned short* __restrict__ Seqp)
{
  __shared__ unsigned short lds[2][20 * 512]; // 20 segments x 1KB, double-buffered
  const int tid = threadIdx.x, lane = tid & 63, w = tid >> 6;
  const int bx = blockIdx.x, by = blockIdx.y;
  const int wm = w >> 1, wn = w & 1;

  f32x4 acc[6][2] = {}; // [ih_r,ih_z,ih_n,hh_r,hh_z,hh_n][m-frag]

  auto stage = [&](int buf, int kb) {
    #pragma unroll
    for (int r = 0; r < 5; ++r) {
      int s = w + r * 4; // wave-uniform segment id 0..19
      const unsigned short* src;
      if (s < 4) {
        src = Xp + (((size_t)bx * 32 + kb) * 4 + s) * 512 + lane * 8;
      } else if (s < 8) {
        src = Hp + (((size_t)bx * 32 + kb) * 4 + (s - 4)) * 512 + lane * 8;
      } else {
        int t6 = s - 8, tb = t6 >> 1, half = t6 & 1;
        int g = tb % 3;
        const unsigned short* W = (tb < 3) ? Wih : Whh;
        int n0 = n_base + g * 1024 + by * 32;
        int n_blk = n0 >> 6, st0 = (n0 >> 4) & 3;
        src = W + (((size_t)n_blk * 32 + kb) * 4 + st0 + half) * 512 + lane * 8;
      }
      unsigned short* dst = &lds[buf][s * 512 + lane * 8];
      GLOAD16(src, dst);
    }
  };

  stage(0, 0);
  __syncthreads();
  int cur = 0;
  for (int kb = 0; kb < 32; ++kb) {
    if (kb + 1 < 32) stage(cur ^ 1, kb + 1);
    const unsigned short* L = lds[cur];
    bf16x8 ax0 = *(const bf16x8*)(L + (wm * 2 + 0) * 512 + lane * 8);
    bf16x8 ax1 = *(const bf16x8*)(L + (wm * 2 + 1) * 512 + lane * 8);
    bf16x8 ah0 = *(const bf16x8*)(L + 2048 + (wm * 2 + 0) * 512 + lane * 8);
    bf16x8 ah1 = *(const bf16x8*)(L + 2048 + (wm * 2 + 1) * 512 + lane * 8);
    #pragma unroll
    for (int tb = 0; tb < 6; ++tb) {
      bf16x8 bf = *(const bf16x8*)(L + 4096 + tb * 1024 + wn * 512 + lane * 8);
      bf16x8 a0 = (tb < 3) ? ax0 : ah0;
      bf16x8 a1 = (tb < 3) ? ax1 : ah1;
      acc[tb][0] = MFMA16(a0, bf, acc[tb][0]);
      acc[tb][1] = MFMA16(a1, bf, acc[tb][1]);
    }
    __syncthreads();
    cur ^= 1;
  }

  // epilogue: full GRU gate math
  const int d = by * 32 + wn * 16 + (lane & 15);
  const float bi_r = bih[d], bi_z = bih[D_ + d], bi_n = bih[2 * D_ + d];
  const float bh_r = bhh[d], bh_z = bhh[D_ + d], bh_n = bhh[2 * D_ + d];
  #pragma unroll
  for (int fm = 0; fm < 2; ++fm) {
    #pragma unroll
    for (int q = 0; q < 4; ++q) {
      int m = bx * 64 + wm * 32 + fm * 16 + ((lane >> 4) << 2) + q;
      float rr = 1.f / (1.f + __expf(-(acc[0][fm][q] + bi_r + acc[3][fm][q] + bh_r)));
      float zz = 1.f / (1.f + __expf(-(acc[1][fm][q] + bi_z + acc[4][fm][q] + bh_z)));
      float nn = tanhf(acc[2][fm][q] + bi_n + rr * (acc[5][fm][q] + bh_n));
      float h  = Hf[(size_t)m * D_ + d];
      float hnew = (1.f - zz) * nn + zz * h;
      Hf_out[(size_t)m * D_ + d] = hnew;
      unsigned short hb = f2b(hnew);
      size_t pi = pidx(m, d, D_);
      Hp_out[pi] = hb;
      if (WRITE_SEQ) Seqp[pi] = hb;
    }
  }
}

// ================= generic packed NT MFMA GEMM =================
// C = A(MxK) @ W(NxK)^T, both packed bf16. BM=BN=64, BK=32, 4 waves (2x2), wave=32x32.
// EPI 0: encoder embed  (+b_data+time+day, write packed X slot t+1)
// EPI 1: decoder embed  (+b_data+time+day, write packed XIp)
// EPI 2: mlp head       (+b_mlp+DC, write dout & DC & packed DCp; n<325)
template<int EPI>
__global__ __launch_bounds__(256) void gemm_packed(
    const unsigned short* __restrict__ Ap, const unsigned short* __restrict__ Wp, int K32,
    const float* __restrict__ bias,
    const float* __restrict__ time_table, const float* __restrict__ day_table,
    const int* __restrict__ timev, const int* __restrict__ weekday,
    unsigned short* __restrict__ outp, int step,
    float* __restrict__ DC, float* __restrict__ dout, unsigned short* __restrict__ DCp)
{
  __shared__ unsigned short lds[2][8 * 512];
  const int tid = threadIdx.x, lane = tid & 63, w = tid >> 6;
  const int bx = blockIdx.x, by = blockIdx.y;
  const int wm = w >> 1, wn = w & 1;
  f32x4 acc[2][2] = {};

  auto stage = [&](int buf, int kb) {
    #pragma unroll
    for (int r = 0; r < 2; ++r) {
      int s = w + r * 4;
      const unsigned short* src = (s < 4)
          ? Ap + (((size_t)bx * K32 + kb) * 4 + s) * 512 + lane * 8
          : Wp + (((size_t)by * K32 + kb) * 4 + (s - 4)) * 512 + lane * 8;
      unsigned short* dst = &lds[buf][s * 512 + lane * 8];
      GLOAD16(src, dst);
    }
  };

  stage(0, 0);
  __syncthreads();
  int cur = 0;
  for (int kb = 0; kb < K32; ++kb) {
    if (kb + 1 < K32) stage(cur ^ 1, kb + 1);
    const unsigned short* L = lds[cur];
    bf16x8 a0 = *(const bf16x8*)(L + (wm * 2 + 0) * 512 + lane * 8);
    bf16x8 a1 = *(const bf16x8*)(L + (wm * 2 + 1) * 512 + lane * 8);
    bf16x8 b0 = *(const bf16x8*)(L + 2048 + (wn * 2 + 0) * 512 + lane * 8);
    bf16x8 b1 = *(const bf16x8*)(L + 2048 + (wn * 2 + 1) * 512 + lane * 8);
    acc[0][0] = MFMA16(a0, b0, acc[0][0]);
    acc[0][1] = MFMA16(a0, b1, acc[0][1]);
    acc[1][0] = MFMA16(a1, b0, acc[1][0]);
    acc[1][1] = MFMA16(a1, b1, acc[1][1]);
    __syncthreads();
    cur ^= 1;
  }

  #pragma unroll
  for (int fm = 0; fm < 2; ++fm) {
    #pragma unroll
    for (int q = 0; q < 4; ++q) {
      int m = bx * 64 + wm * 32 + fm * 16 + ((lane >> 4) << 2) + q;
      int bb, ti = 0, di = 0; size_t obase = 0;
      if (EPI == 0) {
        bb = m / 23; int t = m - bb * 23;
        ti = timev[bb * T_ + t] % 288; di = weekday[bb];
        obase = (size_t)(t + 1) * (512 * 1024);
      } else {
        bb = m;
        if (EPI == 1) { ti = (timev[bb * T_ + (T_ - 1)] + step) % 288; di = weekday[bb]; }
      }
      #pragma unroll
      for (int fn = 0; fn < 2; ++fn) {
        int n = by * 64 + wn * 32 + fn * 16 + (lane & 15);
        float v = acc[fm][fn][q];
        if (EPI <= 1) {
          v += bias[n] + time_table[(size_t)ti * D_ + n] + day_table[(size_t)di * D_ + n];
          if (EPI == 0) outp[obase + pidx(bb, n, 1024)] = f2b(v);
          else          outp[pidx(bb, n, 1024)] = f2b(v);
        } else {
          if (n < OUT_) {
            v += bias[n] + DC[bb * OUT_ + n];
            dout[((size_t)bb * HORIZON_ + step) * OUT_ + n] = v;
            DC[bb * OUT_ + n] = v;
            DCp[pidx(bb, n, 352)] = f2b(v);
          }
        }
      }
    }
  }
}

// ================= pack / cast kernels =================
__global__ void pack_nt(const float* __restrict__ src, unsigned short* __restrict__ dst, int total) {
  int stride = gridDim.x * 256;
  for (int i = blockIdx.x * 256 + threadIdx.x; i < total; i += stride) {
    int n = i >> 10, k = i & 1023;
    dst[pidx(n, k, 1024)] = f2b(src[i]);
  }
}
__global__ void pack_wd(const float* __restrict__ w_data, unsigned short* __restrict__ dst) {
  int stride = gridDim.x * 256;
  for (int i = blockIdx.x * 256 + threadIdx.x; i < 1024 * 352; i += stride) {
    int n = i / 352, k = i - n * 352;
    float v = (k < OUT_) ? w_data[(size_t)k * 1024 + n] : 0.f;
    dst[pidx(n, k, 352)] = f2b(v);
  }
}
__global__ void pack_wm(const float* __restrict__ w_mlp, unsigned short* __restrict__ dst) {
  int stride = gridDim.x * 256;
  for (int i = blockIdx.x * 256 + threadIdx.x; i < 384 * 1024; i += stride) {
    int n = i >> 10, k = i & 1023;
    float v = (n < OUT_) ? w_mlp[(size_t)k * OUT_ + n] : 0.f;
    dst[pidx(n, k, 1024)] = f2b(v);
  }
}
__global__ void pack_ae(const float* __restrict__ data, unsigned short* __restrict__ Ap) {
  int stride = gridDim.x * 256;
  for (int i = blockIdx.x * 256 + threadIdx.x; i < 11776 * 352; i += stride) {
    int m = i / 352, k = i - m * 352;
    int b = m / 23, t = m - b * 23;
    float v = (k < OUT_) ? data[((size_t)b * T_ + t) * OUT_ + k] : 0.f;
    Ap[pidx(m, k, 352)] = f2b(v);
  }
}
__global__ void pack_dc(const float* __restrict__ data, unsigned short* __restrict__ DCp,
                        float* __restrict__ DC) {
  int stride = gridDim.x * 256;
  for (int i = blockIdx.x * 256 + threadIdx.x; i < 512 * 352; i += stride) {
    int b = i / 352, k = i - b * 352;
    float v = (k < OUT_) ? data[((size_t)b * T_ + (T_ - 1)) * OUT_ + k] : 0.f;
    DCp[pidx(b, k, 352)] = f2b(v);
    if (k < OUT_) DC[b * OUT_ + k] = v;
  }
}

extern "C" void kernel_launch(void* const* d_in, const int* in_sizes, int n_in,
                              void* d_out, int out_size, void* d_ws, size_t ws_size,
                              hipStream_t stream) {
  const float* data       = (const float*)d_in[0];
  const int*   timev      = (const int*)  d_in[1];
  const int*   weekday    = (const int*)  d_in[2];
  const float* w_data     = (const float*)d_in[3];
  const float* b_data     = (const float*)d_in[4];
  const float* time_table = (const float*)d_in[5];
  const float* day_table  = (const float*)d_in[6];
  const float* enc_Wih    = (const float*)d_in[7];
  const float* enc_Whh    = (const float*)d_in[8];
  const float* enc_bih    = (const float*)d_in[9];
  const float* enc_bhh    = (const float*)d_in[10];
  const float* dec_Wih    = (const float*)d_in[11];
  const float* dec_Whh    = (const float*)d_in[12];
  const float* dec_bih    = (const float*)d_in[13];
  const float* dec_bhh    = (const float*)d_in[14];
  const float* w_mlp      = (const float*)d_in[15];
  const float* b_mlp      = (const float*)d_in[16];
  float* out = (float*)d_out;

  char* base = (char*)d_ws;
  size_t o = 0;
  auto take = [&](size_t bytes) { void* p = base + o; o = (o + bytes + 511) & ~(size_t)511; return p; };
  const size_t WSZ = (size_t)6144 * 1024 * 2;
  unsigned short* Wih_e = (unsigned short*)take(WSZ);
  unsigned short* Whh_e = (unsigned short*)take(WSZ);
  unsigned short* Wih_d = (unsigned short*)take(WSZ);
  unsigned short* Whh_d = (unsigned short*)take(WSZ);
  unsigned short* WdT   = (unsigned short*)take((size_t)1024 * 352 * 2);
  unsigned short* WmT   = (unsigned short*)take((size_t)384 * 1024 * 2);
  unsigned short* Xp    = (unsigned short*)take((size_t)24 * 512 * 1024 * 2); // 24 slots
  unsigned short* XIp   = (unsigned short*)take((size_t)512 * 1024 * 2);
  unsigned short* DCp   = (unsigned short*)take((size_t)512 * 352 * 2);
  float*          DC    = (float*)take((size_t)512 * OUT_ * 4);
  float*          Hfb   = (float*)take((size_t)4 * 512 * 1024 * 4 + (size_t)4 * 512 * 1024 * 2);
  if (o > ws_size) return; // ~92 MB required

  float* Hf[2][2]; unsigned short* Hp[2][2];
  unsigned short* Hpb = (unsigned short*)(Hfb + (size_t)4 * 512 * 1024);
  for (int l = 0; l < 2; ++l)
    for (int p = 0; p < 2; ++p) {
      Hf[l][p] = Hfb + (size_t)(l * 2 + p) * 512 * 1024;
      Hp[l][p] = Hpb + (size_t)(l * 2 + p) * 512 * 1024;
    }
  // Ap (8.3 MB) aliases the H region (12.6 MB): consumed by the embed GEMM
  // before the H memsets + cell kernels touch H.
  unsigned short* Ap = (unsigned short*)Hfb;

  // ---- packs
  pack_nt<<<4096, 256, 0, stream>>>(enc_Wih, Wih_e, 6144 * 1024);
  pack_nt<<<4096, 256, 0, stream>>>(enc_Whh, Whh_e, 6144 * 1024);
  pack_nt<<<4096, 256, 0, stream>>>(dec_Wih, Wih_d, 6144 * 1024);
  pack_nt<<<4096, 256, 0, stream>>>(dec_Whh, Whh_d, 6144 * 1024);
  pack_wd<<<1024, 256, 0, stream>>>(w_data, WdT);
  pack_wm<<<1024, 256, 0, stream>>>(w_mlp, WmT);
  pack_ae<<<4096, 256, 0, stream>>>(data, Ap);
  pack_dc<<<512, 256, 0, stream>>>(data, DCp, DC);

  // ---- batched encoder embed -> X slots 1..23
  gemm_packed<0><<<dim3(184, 16), 256, 0, stream>>>(
      Ap, WdT, 11, b_data, time_table, day_table, timev, weekday, Xp, 0,
      nullptr, nullptr, nullptr);

  // ---- zero initial hidden states (after embed GEMM: Ap alias released)
  hipMemsetAsync(Hf[0][0], 0, (size_t)512 * 1024 * 4, stream);
  hipMemsetAsync(Hf[1][0], 0, (size_t)512 * 1024 * 4, stream);
  hipMemsetAsync(Hp[0][0], 0, (size_t)512 * 1024 * 2, stream);
  hipMemsetAsync(Hp[1][0], 0, (size_t)512 * 1024 * 2, stream);

  const size_t SLOT = (size_t)512 * 1024;
  int pl[2] = {0, 0};

  // ---- encoder: layer 0 reads slot t+1, writes slot t; layer 1 reads slot t
  for (int t = 0; t < TM1; ++t) {
    int p = pl[0];
    gru_cell<1><<<dim3(8, 32), 256, 0, stream>>>(
        Xp + (size_t)(t + 1) * SLOT, Hp[0][p], Hf[0][p],
        Wih_e, Whh_e, 0, enc_bih, enc_bhh,
        Hf[0][1 - p], Hp[0][1 - p], Xp + (size_t)t * SLOT);
    pl[0] ^= 1;
  }
  for (int t = 0; t < TM1; ++t) {
    int p = pl[1];
    gru_cell<0><<<dim3(8, 32), 256, 0, stream>>>(
        Xp + (size_t)t * SLOT, Hp[1][p], Hf[1][p],
        Wih_e, Whh_e, 3072, enc_bih + 3072, enc_bhh + 3072,
        Hf[1][1 - p], Hp[1][1 - p], nullptr);
    pl[1] ^= 1;
  }

  // ---- decoder
  for (int s = 0; s < HORIZON_; ++s) {
    gemm_packed<1><<<dim3(8, 16), 256, 0, stream>>>(
        DCp, WdT, 11, b_data, time_table, day_table, timev, weekday, XIp, s,
        nullptr, nullptr, nullptr);
    int p0 = pl[0];
    gru_cell<0><<<dim3(8, 32), 256, 0, stream>>>(
        XIp, Hp[0][p0], Hf[0][p0], Wih_d, Whh_d, 0, dec_bih, dec_bhh,
        Hf[0][1 - p0], Hp[0][1 - p0], nullptr);
    pl[0] ^= 1; p0 = pl[0];
    int p1 = pl[1];
    gru_cell<0><<<dim3(8, 32), 256, 0, stream>>>(
        Hp[0][p0], Hp[1][p1], Hf[1][p1], Wih_d, Whh_d, 3072,
        dec_bih + 3072, dec_bhh + 3072,
        Hf[1][1 - p1], Hp[1][1 - p1], nullptr);
    pl[1] ^= 1; p1 = pl[1];
    gemm_packed<2><<<dim3(8, 6), 256, 0, stream>>>(
        Hp[1][p1], WmT, 32, b_mlp, nullptr, nullptr, nullptr, nullptr,
        nullptr, s, DC, out, DCp);
  }
}

// Round 3
// 2069.944 us; speedup vs baseline: 6.0685x; 1.0300x over previous
//
#include <hip/hip_runtime.h>
#include <math.h>

#define B_ 512
#define T_ 24
#define TM1 23
#define D_ 1024
#define OUT_ 325
#define HORIZON_ 12

typedef __attribute__((ext_vector_type(8))) short bf16x8;
typedef __attribute__((ext_vector_type(4))) float f32x4;

#define MFMA16(a, b, c) __builtin_amdgcn_mfma_f32_16x16x32_bf16((a), (b), (c), 0, 0, 0)

__device__ __forceinline__ unsigned short f2b(float f) {
  union { float f; unsigned u; } v; v.f = f;
  unsigned r = (v.u + 0x7fffu + ((v.u >> 16) & 1u)) >> 16;
  return (unsigned short)r;
}
__device__ __forceinline__ float b2f(unsigned short s) {
  union { unsigned u; float f; } v; v.u = ((unsigned)s) << 16;
  return v.f;
}

// Packed fragment layout for an (M x K) bf16 matrix, M%64==0, K%32==0.
// Segment (m_blk, k_blk, st) is 512 contiguous elems = one wave-load (1KB):
// lane l, elem j  <->  row m_blk*64+st*16+(l&15), col k_blk*32+(l>>4)*8+j
__device__ __forceinline__ size_t pidx(int m, int k, int K) {
  return ((((size_t)(m >> 6) * (K >> 5) + (k >> 5)) * 4 + ((m >> 4) & 3)) * 64
          + ((m & 15) + (((k >> 3) & 3) << 4))) * 8 + (k & 7);
}

#define GLOAD16(src, dst) \
  __builtin_amdgcn_global_load_lds((const __attribute__((address_space(1))) void*)(src), \
                                   (__attribute__((address_space(3))) void*)(dst), 16, 0, 0)

// ================= fused GRU cell (full: gx + gh) — used by decoder =========
template<int WRITE_SEQ>
__global__ __launch_bounds__(256) void gru_cell(
    const unsigned short* __restrict__ Xp,
    const unsigned short* __restrict__ Hp,
    const float* __restrict__ Hf,
    const unsigned short* __restrict__ Wih,
    const unsigned short* __restrict__ Whh,
    int n_base,
    const float* __restrict__ bih, const float* __restrict__ bhh,
    float* __restrict__ Hf_out, unsigned short* __restrict__ Hp_out,
    unsigned short* __restrict__ Seqp)
{
  __shared__ unsigned short lds[2][20 * 512];
  const int tid = threadIdx.x, lane = tid & 63, w = tid >> 6;
  const int bx = blockIdx.x, by = blockIdx.y;
  const int wm = w >> 1, wn = w & 1;

  f32x4 acc[6][2] = {};

  auto stage = [&](int buf, int kb) {
    #pragma unroll
    for (int r = 0; r < 5; ++r) {
      int s = w + r * 4;
      const unsigned short* src;
      if (s < 4) {
        src = Xp + (((size_t)bx * 32 + kb) * 4 + s) * 512 + lane * 8;
      } else if (s < 8) {
        src = Hp + (((size_t)bx * 32 + kb) * 4 + (s - 4)) * 512 + lane * 8;
      } else {
        int t6 = s - 8, tb = t6 >> 1, half = t6 & 1;
        int g = tb % 3;
        const unsigned short* W = (tb < 3) ? Wih : Whh;
        int n0 = n_base + g * 1024 + by * 32;
        int n_blk = n0 >> 6, st0 = (n0 >> 4) & 3;
        src = W + (((size_t)n_blk * 32 + kb) * 4 + st0 + half) * 512 + lane * 8;
      }
      unsigned short* dst = &lds[buf][s * 512 + lane * 8];
      GLOAD16(src, dst);
    }
  };

  stage(0, 0);
  __syncthreads();
  int cur = 0;
  for (int kb = 0; kb < 32; ++kb) {
    if (kb + 1 < 32) stage(cur ^ 1, kb + 1);
    const unsigned short* L = lds[cur];
    bf16x8 ax0 = *(const bf16x8*)(L + (wm * 2 + 0) * 512 + lane * 8);
    bf16x8 ax1 = *(const bf16x8*)(L + (wm * 2 + 1) * 512 + lane * 8);
    bf16x8 ah0 = *(const bf16x8*)(L + 2048 + (wm * 2 + 0) * 512 + lane * 8);
    bf16x8 ah1 = *(const bf16x8*)(L + 2048 + (wm * 2 + 1) * 512 + lane * 8);
    #pragma unroll
    for (int tb = 0; tb < 6; ++tb) {
      bf16x8 bf = *(const bf16x8*)(L + 4096 + tb * 1024 + wn * 512 + lane * 8);
      bf16x8 a0 = (tb < 3) ? ax0 : ah0;
      bf16x8 a1 = (tb < 3) ? ax1 : ah1;
      acc[tb][0] = MFMA16(a0, bf, acc[tb][0]);
      acc[tb][1] = MFMA16(a1, bf, acc[tb][1]);
    }
    __syncthreads();
    cur ^= 1;
  }

  const int d = by * 32 + wn * 16 + (lane & 15);
  const float bi_r = bih[d], bi_z = bih[D_ + d], bi_n = bih[2 * D_ + d];
  const float bh_r = bhh[d], bh_z = bhh[D_ + d], bh_n = bhh[2 * D_ + d];
  #pragma unroll
  for (int fm = 0; fm < 2; ++fm) {
    #pragma unroll
    for (int q = 0; q < 4; ++q) {
      int m = bx * 64 + wm * 32 + fm * 16 + ((lane >> 4) << 2) + q;
      float rr = 1.f / (1.f + __expf(-(acc[0][fm][q] + bi_r + acc[3][fm][q] + bh_r)));
      float zz = 1.f / (1.f + __expf(-(acc[1][fm][q] + bi_z + acc[4][fm][q] + bh_z)));
      float nn = tanhf(acc[2][fm][q] + bi_n + rr * (acc[5][fm][q] + bh_n));
      float h  = Hf[(size_t)m * D_ + d];
      float hnew = (1.f - zz) * nn + zz * h;
      Hf_out[(size_t)m * D_ + d] = hnew;
      unsigned short hb = f2b(hnew);
      size_t pi = pidx(m, d, D_);
      Hp_out[pi] = hb;
      if (WRITE_SEQ) Seqp[pi] = hb;
    }
  }
}

// ================= gh-only GRU h-step (encoder scan) =================
// gh = h@Whh^T via MFMA; gx read precomputed (bf16, bih folded).
// Grid (8,32), 256 thr = 4 waves (2x2); block tile 64 rows x 32 d-cols.
template<int WRITE_SEQ>
__global__ __launch_bounds__(256) void gru_hcell(
    const unsigned short* __restrict__ Hp,
    const float* __restrict__ Hf,
    const unsigned short* __restrict__ Whh_l,   // packed 3072x1024, layer pre-offset
    const float* __restrict__ bhh_l,
    const unsigned short* __restrict__ GXslot,  // bf16 [512][3072], bih folded
    float* __restrict__ Hf_out, unsigned short* __restrict__ Hp_out,
    unsigned short* __restrict__ Seqp)
{
  __shared__ unsigned short lds[2][10 * 512]; // 20 KB
  const int tid = threadIdx.x, lane = tid & 63, w = tid >> 6;
  const int bx = blockIdx.x, by = blockIdx.y;
  const int wm = w >> 1, wn = w & 1;

  f32x4 acc[3][2] = {};

  auto stage = [&](int buf, int kb) {
    // s 0..3: H segs; s 4..9: Whh segs (gate g = (s-4)>>1, half = (s-4)&1)
    {
      int s = w;
      const unsigned short* src = Hp + (((size_t)bx * 32 + kb) * 4 + s) * 512 + lane * 8;
      GLOAD16(src, &lds[buf][s * 512 + lane * 8]);
    }
    {
      int s = 4 + w;
      int g = w >> 1, half = w & 1;
      int n_blk = g * 16 + (by >> 1), st = (by & 1) * 2 + half;
      const unsigned short* src = Whh_l + (((size_t)n_blk * 32 + kb) * 4 + st) * 512 + lane * 8;
      GLOAD16(src, &lds[buf][s * 512 + lane * 8]);
    }
    if (w < 2) {
      int s = 8 + w;
      int half = w;
      int n_blk = 2 * 16 + (by >> 1), st = (by & 1) * 2 + half;
      const unsigned short* src = Whh_l + (((size_t)n_blk * 32 + kb) * 4 + st) * 512 + lane * 8;
      GLOAD16(src, &lds[buf][s * 512 + lane * 8]);
    }
  };

  stage(0, 0);
  __syncthreads();
  int cur = 0;
  for (int kb = 0; kb < 32; ++kb) {
    if (kb + 1 < 32) stage(cur ^ 1, kb + 1);
    const unsigned short* L = lds[cur];
    bf16x8 a0 = *(const bf16x8*)(L + (wm * 2 + 0) * 512 + lane * 8);
    bf16x8 a1 = *(const bf16x8*)(L + (wm * 2 + 1) * 512 + lane * 8);
    #pragma unroll
    for (int g = 0; g < 3; ++g) {
      bf16x8 bf = *(const bf16x8*)(L + (4 + g * 2 + wn) * 512 + lane * 8);
      acc[g][0] = MFMA16(a0, bf, acc[g][0]);
      acc[g][1] = MFMA16(a1, bf, acc[g][1]);
    }
    __syncthreads();
    cur ^= 1;
  }

  const int d = by * 32 + wn * 16 + (lane & 15);
  const float bh_r = bhh_l[d], bh_z = bhh_l[D_ + d], bh_n = bhh_l[2 * D_ + d];
  #pragma unroll
  for (int fm = 0; fm < 2; ++fm) {
    #pragma unroll
    for (int q = 0; q < 4; ++q) {
      int m = bx * 64 + wm * 32 + fm * 16 + ((lane >> 4) << 2) + q;
      const unsigned short* gxp = GXslot + (size_t)m * 3072 + d;
      float gx_r = b2f(gxp[0]);
      float gx_z = b2f(gxp[D_]);
      float gx_n = b2f(gxp[2 * D_]);
      float rr = 1.f / (1.f + __expf(-(gx_r + acc[0][fm][q] + bh_r)));
      float zz = 1.f / (1.f + __expf(-(gx_z + acc[1][fm][q] + bh_z)));
      float nn = tanhf(gx_n + rr * (acc[2][fm][q] + bh_n));
      float h  = Hf[(size_t)m * D_ + d];
      float hnew = (1.f - zz) * nn + zz * h;
      Hf_out[(size_t)m * D_ + d] = hnew;
      unsigned short hb = f2b(hnew);
      size_t pi = pidx(m, d, D_);
      Hp_out[pi] = hb;
      if (WRITE_SEQ) Seqp[pi] = hb;
    }
  }
}

// ================= 128x128-tile NT MFMA GEMM for batched gx =================
// C[m,n] = sum_k A[m,k] W[n,k] + bias[n], written bf16 row-major (pitch 3072).
// K=1024 (32 kb). Grid (M/128, 24). 256 thr = 4 waves (2x2), wave = 64x64.
__global__ __launch_bounds__(256) void gemm128_gx(
    const unsigned short* __restrict__ Ap,   // packed M x 1024
    const unsigned short* __restrict__ Wp,   // packed 3072 x 1024 (layer pre-offset)
    const float* __restrict__ bias,          // bih (layer pre-offset)
    unsigned short* __restrict__ GX)         // [M][3072] bf16
{
  __shared__ unsigned short lds[2][16 * 512]; // 32 KB
  const int tid = threadIdx.x, lane = tid & 63, w = tid >> 6;
  const int bx = blockIdx.x, by = blockIdx.y;
  const int wm = w >> 1, wn = w & 1;

  f32x4 acc[4][4] = {};

  auto stage = [&](int buf, int kb) {
    #pragma unroll
    for (int r = 0; r < 4; ++r) {
      int s = w + r * 4;
      const unsigned short* src;
      if (s < 8) {
        int m_blk = bx * 2 + (s >> 2), st = s & 3;
        src = Ap + (((size_t)m_blk * 32 + kb) * 4 + st) * 512 + lane * 8;
      } else {
        int n_blk = by * 2 + ((s - 8) >> 2), st = (s - 8) & 3;
        src = Wp + (((size_t)n_blk * 32 + kb) * 4 + st) * 512 + lane * 8;
      }
      GLOAD16(src, &lds[buf][s * 512 + lane * 8]);
    }
  };

  stage(0, 0);
  __syncthreads();
  int cur = 0;
  for (int kb = 0; kb < 32; ++kb) {
    if (kb + 1 < 32) stage(cur ^ 1, kb + 1);
    const unsigned short* L = lds[cur];
    bf16x8 af[4], bf[4];
    #pragma unroll
    for (int f = 0; f < 4; ++f) {
      af[f] = *(const bf16x8*)(L + (wm * 4 + f) * 512 + lane * 8);
      bf[f] = *(const bf16x8*)(L + (8 + wn * 4 + f) * 512 + lane * 8);
    }
    #pragma unroll
    for (int fm = 0; fm < 4; ++fm)
      #pragma unroll
      for (int fn = 0; fn < 4; ++fn)
        acc[fm][fn] = MFMA16(af[fm], bf[fn], acc[fm][fn]);
    __syncthreads();
    cur ^= 1;
  }

  #pragma unroll
  for (int fm = 0; fm < 4; ++fm) {
    #pragma unroll
    for (int q = 0; q < 4; ++q) {
      int m = bx * 128 + wm * 64 + fm * 16 + ((lane >> 4) << 2) + q;
      #pragma unroll
      for (int fn = 0; fn < 4; ++fn) {
        int n = by * 128 + wn * 64 + fn * 16 + (lane & 15);
        GX[(size_t)m * 3072 + n] = f2b(acc[fm][fn][q] + bias[n]);
      }
    }
  }
}

// ================= generic packed NT MFMA GEMM (64x64) =================
template<int EPI>
__global__ __launch_bounds__(256) void gemm_packed(
    const unsigned short* __restrict__ Ap, const unsigned short* __restrict__ Wp, int K32,
    const float* __restrict__ bias,
    const float* __restrict__ time_table, const float* __restrict__ day_table,
    const int* __restrict__ timev, const int* __restrict__ weekday,
    unsigned short* __restrict__ outp, int step,
    float* __restrict__ DC, float* __restrict__ dout, unsigned short* __restrict__ DCp)
{
  __shared__ unsigned short lds[2][8 * 512];
  const int tid = threadIdx.x, lane = tid & 63, w = tid >> 6;
  const int bx = blockIdx.x, by = blockIdx.y;
  const int wm = w >> 1, wn = w & 1;
  f32x4 acc[2][2] = {};

  auto stage = [&](int buf, int kb) {
    #pragma unroll
    for (int r = 0; r < 2; ++r) {
      int s = w + r * 4;
      const unsigned short* src = (s < 4)
          ? Ap + (((size_t)bx * K32 + kb) * 4 + s) * 512 + lane * 8
          : Wp + (((size_t)by * K32 + kb) * 4 + (s - 4)) * 512 + lane * 8;
      GLOAD16(src, &lds[buf][s * 512 + lane * 8]);
    }
  };

  stage(0, 0);
  __syncthreads();
  int cur = 0;
  for (int kb = 0; kb < K32; ++kb) {
    if (kb + 1 < K32) stage(cur ^ 1, kb + 1);
    const unsigned short* L = lds[cur];
    bf16x8 a0 = *(const bf16x8*)(L + (wm * 2 + 0) * 512 + lane * 8);
    bf16x8 a1 = *(const bf16x8*)(L + (wm * 2 + 1) * 512 + lane * 8);
    bf16x8 b0 = *(const bf16x8*)(L + 2048 + (wn * 2 + 0) * 512 + lane * 8);
    bf16x8 b1 = *(const bf16x8*)(L + 2048 + (wn * 2 + 1) * 512 + lane * 8);
    acc[0][0] = MFMA16(a0, b0, acc[0][0]);
    acc[0][1] = MFMA16(a0, b1, acc[0][1]);
    acc[1][0] = MFMA16(a1, b0, acc[1][0]);
    acc[1][1] = MFMA16(a1, b1, acc[1][1]);
    __syncthreads();
    cur ^= 1;
  }

  #pragma unroll
  for (int fm = 0; fm < 2; ++fm) {
    #pragma unroll
    for (int q = 0; q < 4; ++q) {
      int m = bx * 64 + wm * 32 + fm * 16 + ((lane >> 4) << 2) + q;
      int bb, ti = 0, di = 0; size_t obase = 0;
      if (EPI == 0) {
        bb = m / 23; int t = m - bb * 23;
        ti = timev[bb * T_ + t] % 288; di = weekday[bb];
        obase = (size_t)(t + 1) * (512 * 1024);
      } else {
        bb = m;
        if (EPI == 1) { ti = (timev[bb * T_ + (T_ - 1)] + step) % 288; di = weekday[bb]; }
      }
      #pragma unroll
      for (int fn = 0; fn < 2; ++fn) {
        int n = by * 64 + wn * 32 + fn * 16 + (lane & 15);
        float v = acc[fm][fn][q];
        if (EPI <= 1) {
          v += bias[n] + time_table[(size_t)ti * D_ + n] + day_table[(size_t)di * D_ + n];
          if (EPI == 0) outp[obase + pidx(bb, n, 1024)] = f2b(v);
          else          outp[pidx(bb, n, 1024)] = f2b(v);
        } else {
          if (n < OUT_) {
            v += bias[n] + DC[bb * OUT_ + n];
            dout[((size_t)bb * HORIZON_ + step) * OUT_ + n] = v;
            DC[bb * OUT_ + n] = v;
            DCp[pidx(bb, n, 352)] = f2b(v);
          }
        }
      }
    }
  }
}

// ================= vectorized pack kernels (8 elems / thread) =================
__global__ void pack_nt8(const float* __restrict__ src, unsigned short* __restrict__ dst, int total) {
  int stride = gridDim.x * 256;
  for (int i = blockIdx.x * 256 + threadIdx.x; i < total; i += stride) {
    int n = i >> 7, kg = i & 127;             // K = 1024
    int k0 = kg * 8;
    const float* s = src + (size_t)n * 1024 + k0;
    float4 v0 = *(const float4*)s, v1 = *(const float4*)(s + 4);
    bf16x8 o;
    o[0] = f2b(v0.x); o[1] = f2b(v0.y); o[2] = f2b(v0.z); o[3] = f2b(v0.w);
    o[4] = f2b(v1.x); o[5] = f2b(v1.y); o[6] = f2b(v1.z); o[7] = f2b(v1.w);
    *(bf16x8*)(dst + pidx(n, k0, 1024)) = o;
  }
}
__global__ void pack_wd8(const float* __restrict__ w_data, unsigned short* __restrict__ dst) {
  int stride = gridDim.x * 256;
  for (int i = blockIdx.x * 256 + threadIdx.x; i < 44 * 1024; i += stride) {
    int n = i & 1023, kg = i >> 10;           // dst rows n over D, k over OUT(352)
    int k0 = kg * 8;
    bf16x8 o;
    #pragma unroll
    for (int j = 0; j < 8; ++j) {
      int k = k0 + j;
      o[j] = (k < OUT_) ? f2b(w_data[(size_t)k * D_ + n]) : (short)0;
    }
    *(bf16x8*)(dst + pidx(n, k0, 352)) = o;
  }
}
__global__ void pack_wm8(const float* __restrict__ w_mlp, unsigned short* __restrict__ dst) {
  int stride = gridDim.x * 256;
  for (int i = blockIdx.x * 256 + threadIdx.x; i < 128 * 384; i += stride) {
    int kg = i / 384, n = i - kg * 384;       // dst rows n over OUT(384), k over D
    int k0 = kg * 8;
    bf16x8 o;
    #pragma unroll
    for (int j = 0; j < 8; ++j) {
      int k = k0 + j;
      o[j] = (n < OUT_) ? f2b(w_mlp[(size_t)k * OUT_ + n]) : (short)0;
    }
    *(bf16x8*)(dst + pidx(n, k0, 1024)) = o;
  }
}
__global__ void pack_ae8(const float* __restrict__ data, unsigned short* __restrict__ Ap) {
  int stride = gridDim.x * 256;
  for (int i = blockIdx.x * 256 + threadIdx.x; i < 11776 * 44; i += stride) {
    int m = i / 44, kg = i - m * 44;
    int b = m / 23, t = m - b * 23;
    int k0 = kg * 8;
    const float* s = data + ((size_t)b * T_ + t) * OUT_;
    bf16x8 o;
    #pragma unroll
    for (int j = 0; j < 8; ++j) {
      int k = k0 + j;
      o[j] = (k < OUT_) ? f2b(s[k]) : (short)0;
    }
    *(bf16x8*)(Ap + pidx(m, k0, 352)) = o;
  }
}
__global__ void pack_dc8(const float* __restrict__ data, unsigned short* __restrict__ DCp,
                         float* __restrict__ DC) {
  int stride = gridDim.x * 256;
  for (int i = blockIdx.x * 256 + threadIdx.x; i < 512 * 44; i += stride) {
    int b = i / 44, kg = i - b * 44;
    int k0 = kg * 8;
    const float* s = data + ((size_t)b * T_ + (T_ - 1)) * OUT_;
    bf16x8 o;
    #pragma unroll
    for (int j = 0; j < 8; ++j) {
      int k = k0 + j;
      float v = (k < OUT_) ? s[k] : 0.f;
      o[j] = f2b(v);
      if (k < OUT_) DC[(size_t)b * OUT_ + k] = v;
    }
    *(bf16x8*)(DCp + pidx(b, k0, 352)) = o;
  }
}

extern "C" void kernel_launch(void* const* d_in, const int* in_sizes, int n_in,
                              void* d_out, int out_size, void* d_ws, size_t ws_size,
                              hipStream_t stream) {
  const float* data       = (const float*)d_in[0];
  const int*   timev      = (const int*)  d_in[1];
  const int*   weekday    = (const int*)  d_in[2];
  const float* w_data     = (const float*)d_in[3];
  const float* b_data     = (const float*)d_in[4];
  const float* time_table = (const float*)d_in[5];
  const float* day_table  = (const float*)d_in[6];
  const float* enc_Wih    = (const float*)d_in[7];
  const float* enc_Whh    = (const float*)d_in[8];
  const float* enc_bih    = (const float*)d_in[9];
  const float* enc_bhh    = (const float*)d_in[10];
  const float* dec_Wih    = (const float*)d_in[11];
  const float* dec_Whh    = (const float*)d_in[12];
  const float* dec_bih    = (const float*)d_in[13];
  const float* dec_bhh    = (const float*)d_in[14];
  const float* w_mlp      = (const float*)d_in[15];
  const float* b_mlp      = (const float*)d_in[16];
  float* out = (float*)d_out;

  char* base = (char*)d_ws;
  size_t o = 0;
  auto take = [&](size_t bytes) { void* p = base + o; o = (o + bytes + 511) & ~(size_t)511; return p; };
  const size_t WSZ = (size_t)6144 * 1024 * 2;
  unsigned short* Wih_e = (unsigned short*)take(WSZ);
  unsigned short* Whh_e = (unsigned short*)take(WSZ);
  unsigned short* Wih_d = (unsigned short*)take(WSZ);
  unsigned short* Whh_d = (unsigned short*)take(WSZ);
  unsigned short* WdT   = (unsigned short*)take((size_t)1024 * 352 * 2);
  unsigned short* WmT   = (unsigned short*)take((size_t)384 * 1024 * 2);
  unsigned short* Xp    = (unsigned short*)take((size_t)24 * 512 * 1024 * 2);
  unsigned short* GXbuf = (unsigned short*)take((size_t)23 * 512 * 3072 * 2); // 72 MB
  unsigned short* XIp   = (unsigned short*)take((size_t)512 * 1024 * 2);
  unsigned short* DCp   = (unsigned short*)take((size_t)512 * 352 * 2);
  float*          DC    = (float*)take((size_t)512 * OUT_ * 4);
  float*          Hfb   = (float*)take((size_t)4 * 512 * 1024 * 4 + (size_t)4 * 512 * 1024 * 2);
  if (o > ws_size) return; // ~164 MB required

  float* Hf[2][2]; unsigned short* Hp[2][2];
  unsigned short* Hpb = (unsigned short*)(Hfb + (size_t)4 * 512 * 1024);
  for (int l = 0; l < 2; ++l)
    for (int p = 0; p < 2; ++p) {
      Hf[l][p] = Hfb + (size_t)(l * 2 + p) * 512 * 1024;
      Hp[l][p] = Hpb + (size_t)(l * 2 + p) * 512 * 1024;
    }
  // Ap (8.3 MB) aliases GXbuf (72 MB): consumed by the embed GEMM before
  // gemm128_gx writes GXbuf.
  unsigned short* Ap = GXbuf;

  const size_t SLOT = (size_t)512 * 1024;
  const size_t WLAYER = (size_t)3072 * 1024;
  const size_t GXS = (size_t)512 * 3072;

  // ---- packs
  pack_nt8<<<2048, 256, 0, stream>>>(enc_Wih, Wih_e, 6144 * 128);
  pack_nt8<<<2048, 256, 0, stream>>>(enc_Whh, Whh_e, 6144 * 128);
  pack_nt8<<<2048, 256, 0, stream>>>(dec_Wih, Wih_d, 6144 * 128);
  pack_nt8<<<2048, 256, 0, stream>>>(dec_Whh, Whh_d, 6144 * 128);
  pack_wd8<<<176, 256, 0, stream>>>(w_data, WdT);
  pack_wm8<<<192, 256, 0, stream>>>(w_mlp, WmT);
  pack_ae8<<<2024, 256, 0, stream>>>(data, Ap);
  pack_dc8<<<88, 256, 0, stream>>>(data, DCp, DC);

  // ---- batched encoder embed -> X slots 1..23
  gemm_packed<0><<<dim3(184, 16), 256, 0, stream>>>(
      Ap, WdT, 11, b_data, time_table, day_table, timev, weekday, Xp, 0,
      nullptr, nullptr, nullptr);

  // ---- layer-0 gx: GX = Xemb @ Wih0^T + bih0   (slots 1..23)
  gemm128_gx<<<dim3(92, 24), 256, 0, stream>>>(Xp + SLOT, Wih_e, enc_bih, GXbuf);

  // ---- zero initial hidden states
  hipMemsetAsync(Hf[0][0], 0, (size_t)512 * 1024 * 4, stream);
  hipMemsetAsync(Hf[1][0], 0, (size_t)512 * 1024 * 4, stream);
  hipMemsetAsync(Hp[0][0], 0, (size_t)512 * 1024 * 2, stream);
  hipMemsetAsync(Hp[1][0], 0, (size_t)512 * 1024 * 2, stream);

  int pl[2] = {0, 0};

  // ---- encoder layer 0 scan (writes layer-1 input into slot t)
  for (int t = 0; t < TM1; ++t) {
    int p = pl[0];
    gru_hcell<1><<<dim3(8, 32), 256, 0, stream>>>(
        Hp[0][p], Hf[0][p], Whh_e, enc_bhh,
        GXbuf + (size_t)t * GXS,
        Hf[0][1 - p], Hp[0][1 - p], Xp + (size_t)t * SLOT);
    pl[0] ^= 1;
  }

  // ---- layer-1 gx: GX = Y0 @ Wih1^T + bih1   (slots 0..22)
  gemm128_gx<<<dim3(92, 24), 256, 0, stream>>>(Xp, Wih_e + WLAYER, enc_bih + 3072, GXbuf);

  // ---- encoder layer 1 scan
  for (int t = 0; t < TM1; ++t) {
    int p = pl[1];
    gru_hcell<0><<<dim3(8, 32), 256, 0, stream>>>(
        Hp[1][p], Hf[1][p], Whh_e + WLAYER, enc_bhh + 3072,
        GXbuf + (size_t)t * GXS,
        Hf[1][1 - p], Hp[1][1 - p], nullptr);
    pl[1] ^= 1;
  }

  // ---- decoder
  for (int s = 0; s < HORIZON_; ++s) {
    gemm_packed<1><<<dim3(8, 16), 256, 0, stream>>>(
        DCp, WdT, 11, b_data, time_table, day_table, timev, weekday, XIp, s,
        nullptr, nullptr, nullptr);
    int p0 = pl[0];
    gru_cell<0><<<dim3(8, 32), 256, 0, stream>>>(
        XIp, Hp[0][p0], Hf[0][p0], Wih_d, Whh_d, 0, dec_bih, dec_bhh,
        Hf[0][1 - p0], Hp[0][1 - p0], nullptr);
    pl[0] ^= 1; p0 = pl[0];
    int p1 = pl[1];
    gru_cell<0><<<dim3(8, 32), 256, 0, stream>>>(
        Hp[0][p0], Hp[1][p1], Hf[1][p1], Wih_d, Whh_d, 3072,
        dec_bih + 3072, dec_bhh + 3072,
        Hf[1][1 - p1], Hp[1][1 - p1], nullptr);
    pl[1] ^= 1; p1 = pl[1];
    gemm_packed<2><<<dim3(8, 6), 256, 0, stream>>>(
        Hp[1][p1], WmT, 32, b_mlp, nullptr, nullptr, nullptr, nullptr,
        nullptr, s, DC, out, DCp);
  }
}

// Round 4
// 1982.559 us; speedup vs baseline: 6.3360x; 1.0441x over previous
//
#include <hip/hip_runtime.h>
#include <math.h>

#define B_ 512
#define T_ 24
#define TM1 23
#define D_ 1024
#define OUT_ 325
#define HORIZON_ 12

typedef unsigned short ushort_t;
typedef __attribute__((ext_vector_type(8))) short bf16x8;
typedef __attribute__((ext_vector_type(4))) float f32x4;

#define MFMA16(a, b, c) __builtin_amdgcn_mfma_f32_16x16x32_bf16((a), (b), (c), 0, 0, 0)

__device__ __forceinline__ ushort_t f2b(float f) {
  union { float f; unsigned u; } v; v.f = f;
  unsigned r = (v.u + 0x7fffu + ((v.u >> 16) & 1u)) >> 16;
  return (ushort_t)r;
}
__device__ __forceinline__ float b2f(ushort_t s) {
  union { unsigned u; float f; } v; v.u = ((unsigned)s) << 16;
  return v.f;
}

// 16-row-granular packed fragment layout for (M x K) bf16, M%16==0, K%32==0.
// Segment (m>>4, k>>5) = 512 contiguous elems = one wave 1KB load.
// lane l, elem j <-> row m0+(l&15), col k0+(l>>4)*8+j
__device__ __forceinline__ size_t pidx16(int m, int k, int K) {
  return (((size_t)(m >> 4) * (K >> 5) + (k >> 5)) * 64
          + ((m & 15) + (((k >> 3) & 3) << 4))) * 8 + (k & 7);
}

#define GLOAD16(src, dst) \
  __builtin_amdgcn_global_load_lds((const __attribute__((address_space(1))) void*)(src), \
                                   (__attribute__((address_space(3))) void*)(dst), 16, 0, 0)

// =============== gh-only GRU step: tile 32x32, grid (16,32) = 512 blocks ===============
template<int WRITE_SEQ>
__global__ __launch_bounds__(256) void gru_hcell32(
    const ushort_t* __restrict__ Hp, const float* __restrict__ Hf,
    const ushort_t* __restrict__ Whh_l,   // packed 3072x1024 (layer pre-offset)
    const float* __restrict__ bhh_l,
    const ushort_t* __restrict__ GXslot,  // bf16 [512][3072] row-major, bih folded
    float* __restrict__ Hf_out, ushort_t* __restrict__ Hp_out,
    ushort_t* __restrict__ Seqp)
{
  __shared__ ushort_t lds[2][8 * 512];
  const int tid = threadIdx.x, lane = tid & 63, w = tid >> 6;
  const int bx = blockIdx.x, by = blockIdx.y;
  const int wm = w >> 1, wn = w & 1;
  f32x4 acc[3] = {};

  auto stage = [&](int buf, int kb) {
    #pragma unroll
    for (int r = 0; r < 2; ++r) {
      int s = w * 2 + r;
      const ushort_t* src;
      if (s < 2) {
        src = Hp + ((size_t)(((bx * 32 + s * 16) >> 4) * 32 + kb)) * 512 + lane * 8;
      } else {
        int g = (s - 2) >> 1, hf = (s - 2) & 1;
        src = Whh_l + ((size_t)(((g * 1024 + by * 32 + hf * 16) >> 4) * 32 + kb)) * 512 + lane * 8;
      }
      GLOAD16(src, &lds[buf][s * 512 + lane * 8]);
    }
  };

  stage(0, 0);
  __syncthreads();
  int cur = 0;
  for (int kb = 0; kb < 32; ++kb) {
    if (kb + 1 < 32) stage(cur ^ 1, kb + 1);
    const ushort_t* L = lds[cur];
    bf16x8 a = *(const bf16x8*)(L + wm * 512 + lane * 8);
    #pragma unroll
    for (int g = 0; g < 3; ++g) {
      bf16x8 b = *(const bf16x8*)(L + (2 + g * 2 + wn) * 512 + lane * 8);
      acc[g] = MFMA16(a, b, acc[g]);
    }
    __syncthreads();
    cur ^= 1;
  }

  const int d = by * 32 + wn * 16 + (lane & 15);
  const float bh_r = bhh_l[d], bh_z = bhh_l[D_ + d], bh_n = bhh_l[2 * D_ + d];
  #pragma unroll
  for (int q = 0; q < 4; ++q) {
    int m = bx * 32 + wm * 16 + ((lane >> 4) << 2) + q;
    const ushort_t* gxp = GXslot + (size_t)m * 3072 + d;
    float gx_r = b2f(gxp[0]), gx_z = b2f(gxp[D_]), gx_n = b2f(gxp[2 * D_]);
    float rr = 1.f / (1.f + __expf(-(gx_r + acc[0][q] + bh_r)));
    float zz = 1.f / (1.f + __expf(-(gx_z + acc[1][q] + bh_z)));
    float nn = tanhf(gx_n + rr * (acc[2][q] + bh_n));
    float h  = Hf[(size_t)m * D_ + d];
    float hnew = (1.f - zz) * nn + zz * h;
    Hf_out[(size_t)m * D_ + d] = hnew;
    ushort_t hb = f2b(hnew);
    size_t pi = pidx16(m, d, D_);
    Hp_out[pi] = hb;
    if (WRITE_SEQ) Seqp[pi] = hb;
  }
}

// =============== full GRU cell (gx K=1024 + gh K=1024): tile 32x32 ===============
__global__ __launch_bounds__(256) void gru_cell32(
    const ushort_t* __restrict__ Xp_, const ushort_t* __restrict__ Hp,
    const float* __restrict__ Hf,
    const ushort_t* __restrict__ Wih_l, const ushort_t* __restrict__ Whh_l,
    const float* __restrict__ bih_l, const float* __restrict__ bhh_l,
    float* __restrict__ Hf_out, ushort_t* __restrict__ Hp_out)
{
  __shared__ ushort_t lds[2][16 * 512];
  const int tid = threadIdx.x, lane = tid & 63, w = tid >> 6;
  const int bx = blockIdx.x, by = blockIdx.y;
  const int wm = w >> 1, wn = w & 1;
  f32x4 accx[3] = {}, acch[3] = {};

  auto stage = [&](int buf, int kb) {
    #pragma unroll
    for (int r = 0; r < 4; ++r) {
      int s = w * 4 + r;
      const ushort_t* src;
      if (s < 2) {
        src = Xp_ + ((size_t)(((bx * 32 + s * 16) >> 4) * 32 + kb)) * 512 + lane * 8;
      } else if (s < 4) {
        src = Hp + ((size_t)(((bx * 32 + (s - 2) * 16) >> 4) * 32 + kb)) * 512 + lane * 8;
      } else if (s < 10) {
        int g = (s - 4) >> 1, hf = (s - 4) & 1;
        src = Wih_l + ((size_t)(((g * 1024 + by * 32 + hf * 16) >> 4) * 32 + kb)) * 512 + lane * 8;
      } else {
        int g = (s - 10) >> 1, hf = (s - 10) & 1;
        src = Whh_l + ((size_t)(((g * 1024 + by * 32 + hf * 16) >> 4) * 32 + kb)) * 512 + lane * 8;
      }
      GLOAD16(src, &lds[buf][s * 512 + lane * 8]);
    }
  };

  stage(0, 0);
  __syncthreads();
  int cur = 0;
  for (int kb = 0; kb < 32; ++kb) {
    if (kb + 1 < 32) stage(cur ^ 1, kb + 1);
    const ushort_t* L = lds[cur];
    bf16x8 ax = *(const bf16x8*)(L + (0 + wm) * 512 + lane * 8);
    bf16x8 ah = *(const bf16x8*)(L + (2 + wm) * 512 + lane * 8);
    #pragma unroll
    for (int g = 0; g < 3; ++g) {
      bf16x8 bxw = *(const bf16x8*)(L + (4 + g * 2 + wn) * 512 + lane * 8);
      bf16x8 bhw = *(const bf16x8*)(L + (10 + g * 2 + wn) * 512 + lane * 8);
      accx[g] = MFMA16(ax, bxw, accx[g]);
      acch[g] = MFMA16(ah, bhw, acch[g]);
    }
    __syncthreads();
    cur ^= 1;
  }

  const int d = by * 32 + wn * 16 + (lane & 15);
  const float bi_r = bih_l[d], bi_z = bih_l[D_ + d], bi_n = bih_l[2 * D_ + d];
  const float bh_r = bhh_l[d], bh_z = bhh_l[D_ + d], bh_n = bhh_l[2 * D_ + d];
  #pragma unroll
  for (int q = 0; q < 4; ++q) {
    int m = bx * 32 + wm * 16 + ((lane >> 4) << 2) + q;
    float rr = 1.f / (1.f + __expf(-(accx[0][q] + bi_r + acch[0][q] + bh_r)));
    float zz = 1.f / (1.f + __expf(-(accx[1][q] + bi_z + acch[1][q] + bh_z)));
    float nn = tanhf(accx[2][q] + bi_n + rr * (acch[2][q] + bh_n));
    float h  = Hf[(size_t)m * D_ + d];
    float hnew = (1.f - zz) * nn + zz * h;
    Hf_out[(size_t)m * D_ + d] = hnew;
    Hp_out[pidx16(m, d, D_)] = f2b(hnew);
  }
}

// =============== encoder layer-0 gx via combined weights: 128-tile, K=352 ===============
__global__ __launch_bounds__(256) void gemm_gx0_enc(
    const ushort_t* __restrict__ Ap,   // packed 11776x352 (data)
    const ushort_t* __restrict__ W0p,  // packed 3072x352 (combined)
    const float* __restrict__ CT,      // [320][3072]: 0..287 time', 288..294 day', 295 b_data'
    const float* __restrict__ bih0,
    const int* __restrict__ timev, const int* __restrict__ weekday,
    ushort_t* __restrict__ GX)         // [23*512][3072] bf16 (slot t, row b)
{
  __shared__ ushort_t lds[2][16 * 512];
  const int tid = threadIdx.x, lane = tid & 63, w = tid >> 6;
  const int bx = blockIdx.x, by = blockIdx.y;
  const int wm = w >> 1, wn = w & 1;
  f32x4 acc[4][4] = {};

  auto stage = [&](int buf, int kb) {
    #pragma unroll
    for (int r = 0; r < 4; ++r) {
      int s = r * 4 + w;
      const ushort_t* src = (s < 8)
          ? Ap  + ((size_t)(((bx * 128 + s * 16) >> 4) * 11 + kb)) * 512 + lane * 8
          : W0p + ((size_t)(((by * 128 + (s - 8) * 16) >> 4) * 11 + kb)) * 512 + lane * 8;
      GLOAD16(src, &lds[buf][s * 512 + lane * 8]);
    }
  };

  stage(0, 0);
  __syncthreads();
  int cur = 0;
  for (int kb = 0; kb < 11; ++kb) {
    if (kb + 1 < 11) stage(cur ^ 1, kb + 1);
    const ushort_t* L = lds[cur];
    bf16x8 af[4], bf[4];
    #pragma unroll
    for (int f = 0; f < 4; ++f) {
      af[f] = *(const bf16x8*)(L + (wm * 4 + f) * 512 + lane * 8);
      bf[f] = *(const bf16x8*)(L + (8 + wn * 4 + f) * 512 + lane * 8);
    }
    #pragma unroll
    for (int fm = 0; fm < 4; ++fm)
      #pragma unroll
      for (int fn = 0; fn < 4; ++fn)
        acc[fm][fn] = MFMA16(af[fm], bf[fn], acc[fm][fn]);
    __syncthreads();
    cur ^= 1;
  }

  #pragma unroll
  for (int fm = 0; fm < 4; ++fm) {
    #pragma unroll
    for (int q = 0; q < 4; ++q) {
      int m = bx * 128 + wm * 64 + fm * 16 + ((lane >> 4) << 2) + q;
      int b = m / 23, t = m - b * 23;
      int ti = timev[b * T_ + t] % 288, di = weekday[b];
      const float* ctt = CT + (size_t)ti * 3072;
      const float* ctd = CT + (size_t)(288 + di) * 3072;
      const float* ctb = CT + (size_t)295 * 3072;
      #pragma unroll
      for (int fn = 0; fn < 4; ++fn) {
        int n = by * 128 + wn * 64 + fn * 16 + (lane & 15);
        float v = acc[fm][fn][q] + ctt[n] + ctd[n] + ctb[n] + bih0[n];
        GX[((size_t)t * 512 + b) * 3072 + n] = f2b(v);
      }
    }
  }
}

// =============== encoder layer-1 gx: 128-tile, K=1024, BK=64 ===============
__global__ __launch_bounds__(256) void gemm_gx1(
    const ushort_t* __restrict__ Ap,   // packed 11776x1024 (Y0 in Xp slots)
    const ushort_t* __restrict__ Wp,   // packed 3072x1024 (layer pre-offset)
    const float* __restrict__ bias,
    ushort_t* __restrict__ GX)
{
  __shared__ ushort_t lds[2][32 * 512]; // 32 KB/buf
  const int tid = threadIdx.x, lane = tid & 63, w = tid >> 6;
  const int bx = blockIdx.x, by = blockIdx.y;
  const int wm = w >> 1, wn = w & 1;
  f32x4 acc[4][4] = {};

  auto stage = [&](int buf, int it) {
    #pragma unroll
    for (int r = 0; r < 8; ++r) {
      int s = r * 4 + w;
      int half = s >> 4, t16 = s & 15, kk = t16 >> 3, rs = t16 & 7;
      const ushort_t* base = half ? Wp : Ap;
      int row0 = (half ? by : bx) * 128 + rs * 16;
      const ushort_t* src = base + ((size_t)((row0 >> 4) * 32 + it * 2 + kk)) * 512 + lane * 8;
      GLOAD16(src, &lds[buf][s * 512 + lane * 8]);
    }
  };

  stage(0, 0);
  __syncthreads();
  int cur = 0;
  for (int it = 0; it < 16; ++it) {
    if (it + 1 < 16) stage(cur ^ 1, it + 1);
    const ushort_t* L = lds[cur];
    #pragma unroll
    for (int kk = 0; kk < 2; ++kk) {
      bf16x8 af[4], bf[4];
      #pragma unroll
      for (int f = 0; f < 4; ++f) {
        af[f] = *(const bf16x8*)(L + (kk * 8 + wm * 4 + f) * 512 + lane * 8);
        bf[f] = *(const bf16x8*)(L + (16 + kk * 8 + wn * 4 + f) * 512 + lane * 8);
      }
      #pragma unroll
      for (int fm = 0; fm < 4; ++fm)
        #pragma unroll
        for (int fn = 0; fn < 4; ++fn)
          acc[fm][fn] = MFMA16(af[fm], bf[fn], acc[fm][fn]);
    }
    __syncthreads();
    cur ^= 1;
  }

  #pragma unroll
  for (int fm = 0; fm < 4; ++fm) {
    #pragma unroll
    for (int q = 0; q < 4; ++q) {
      int m = bx * 128 + wm * 64 + fm * 16 + ((lane >> 4) << 2) + q;
      #pragma unroll
      for (int fn = 0; fn < 4; ++fn) {
        int n = by * 128 + wn * 64 + fn * 16 + (lane & 15);
        GX[(size_t)m * 3072 + n] = f2b(acc[fm][fn][q] + bias[n]);
      }
    }
  }
}

// =============== generic 64-tile GEMM with epilogues ===============
// EPI 0: W0' setup   -> outp[pidx16(m,n,352)], n<352
// EPI 1: CT' setup   -> outf[m*3072+n]
// EPI 2: decoder gx0 -> outp[m*3072+n] = acc + CT terms + bias[n]
// EPI 3: mlp head    -> n<325: v=acc+bias[n]+DC; dout, DC, DCp
template<int EPI>
__global__ __launch_bounds__(256) void gemm64(
    const ushort_t* __restrict__ Ap, const ushort_t* __restrict__ Wp, int K32,
    const float* __restrict__ bias, const float* __restrict__ CT,
    const int* __restrict__ timev, const int* __restrict__ weekday, int step,
    ushort_t* __restrict__ outp, float* __restrict__ outf,
    float* __restrict__ dout, ushort_t* __restrict__ DCp)
{
  __shared__ ushort_t lds[2][8 * 512];
  const int tid = threadIdx.x, lane = tid & 63, w = tid >> 6;
  const int bx = blockIdx.x, by = blockIdx.y;
  const int wm = w >> 1, wn = w & 1;
  f32x4 acc[2][2] = {};

  auto stage = [&](int buf, int kb) {
    #pragma unroll
    for (int r = 0; r < 2; ++r) {
      int s = r * 4 + w;
      const ushort_t* src = (s < 4)
          ? Ap + ((size_t)(((bx * 64 + s * 16) >> 4) * K32 + kb)) * 512 + lane * 8
          : Wp + ((size_t)(((by * 64 + (s - 4) * 16) >> 4) * K32 + kb)) * 512 + lane * 8;
      GLOAD16(src, &lds[buf][s * 512 + lane * 8]);
    }
  };

  stage(0, 0);
  __syncthreads();
  int cur = 0;
  for (int kb = 0; kb < K32; ++kb) {
    if (kb + 1 < K32) stage(cur ^ 1, kb + 1);
    const ushort_t* L = lds[cur];
    bf16x8 af[2], bf[2];
    #pragma unroll
    for (int f = 0; f < 2; ++f) {
      af[f] = *(const bf16x8*)(L + (wm * 2 + f) * 512 + lane * 8);
      bf[f] = *(const bf16x8*)(L + (4 + wn * 2 + f) * 512 + lane * 8);
    }
    #pragma unroll
    for (int fm = 0; fm < 2; ++fm)
      #pragma unroll
      for (int fn = 0; fn < 2; ++fn)
        acc[fm][fn] = MFMA16(af[fm], bf[fn], acc[fm][fn]);
    __syncthreads();
    cur ^= 1;
  }

  #pragma unroll
  for (int fm = 0; fm < 2; ++fm) {
    #pragma unroll
    for (int q = 0; q < 4; ++q) {
      int m = bx * 64 + wm * 32 + fm * 16 + ((lane >> 4) << 2) + q;
      int ti = 0, di = 0;
      if (EPI == 2) { ti = (timev[m * T_ + (T_ - 1)] + step) % 288; di = weekday[m]; }
      #pragma unroll
      for (int fn = 0; fn < 2; ++fn) {
        int n = by * 64 + wn * 32 + fn * 16 + (lane & 15);
        float v = acc[fm][fn][q];
        if (EPI == 0) {
          if (n < 352) outp[pidx16(m, n, 352)] = f2b(v);
        } else if (EPI == 1) {
          outf[(size_t)m * 3072 + n] = v;
        } else if (EPI == 2) {
          v += CT[(size_t)ti * 3072 + n] + CT[(size_t)(288 + di) * 3072 + n]
             + CT[(size_t)295 * 3072 + n] + bias[n];
          outp[(size_t)m * 3072 + n] = f2b(v);
        } else {
          if (n < OUT_) {
            v += bias[n] + outf[(size_t)m * OUT_ + n];
            dout[((size_t)m * HORIZON_ + step) * OUT_ + n] = v;
            outf[(size_t)m * OUT_ + n] = v;
            DCp[pidx16(m, n, 352)] = f2b(v);
          }
        }
      }
    }
  }
}

// ================= pack kernels (8 elems / thread, 16-row layout) =================
__global__ void pack_k1024(const float* __restrict__ src, ushort_t* __restrict__ dst,
                           int M, int Mvalid) {
  int stride = gridDim.x * 256;
  int total = M * 128;
  for (int i = blockIdx.x * 256 + threadIdx.x; i < total; i += stride) {
    int n = i >> 7, k0 = (i & 127) * 8;
    bf16x8 o;
    if (n < Mvalid) {
      const float* s = src + (size_t)n * 1024 + k0;
      float4 v0 = *(const float4*)s, v1 = *(const float4*)(s + 4);
      o[0] = f2b(v0.x); o[1] = f2b(v0.y); o[2] = f2b(v0.z); o[3] = f2b(v0.w);
      o[4] = f2b(v1.x); o[5] = f2b(v1.y); o[6] = f2b(v1.z); o[7] = f2b(v1.w);
    } else {
      o = bf16x8{0,0,0,0,0,0,0,0};
    }
    *(bf16x8*)(dst + pidx16(n, k0, 1024)) = o;
  }
}
__global__ void pack_wm(const float* __restrict__ w_mlp, ushort_t* __restrict__ dst) {
  int stride = gridDim.x * 256;
  for (int i = blockIdx.x * 256 + threadIdx.x; i < 384 * 128; i += stride) {
    int n = i >> 7, k0 = (i & 127) * 8;
    bf16x8 o;
    #pragma unroll
    for (int j = 0; j < 8; ++j)
      o[j] = (n < OUT_) ? f2b(w_mlp[(size_t)(k0 + j) * OUT_ + n]) : (short)0;
    *(bf16x8*)(dst + pidx16(n, k0, 1024)) = o;
  }
}
__global__ void pack_ct(const float* __restrict__ time_table, const float* __restrict__ day_table,
                        const float* __restrict__ b_data, ushort_t* __restrict__ dst) {
  int stride = gridDim.x * 256;
  for (int i = blockIdx.x * 256 + threadIdx.x; i < 320 * 128; i += stride) {
    int r = i >> 7, k0 = (i & 127) * 8;
    const float* s = nullptr;
    if (r < 288) s = time_table + (size_t)r * 1024 + k0;
    else if (r < 295) s = day_table + (size_t)(r - 288) * 1024 + k0;
    else if (r == 295) s = b_data + k0;
    bf16x8 o;
    #pragma unroll
    for (int j = 0; j < 8; ++j) o[j] = s ? f2b(s[j]) : (short)0;
    *(bf16x8*)(dst + pidx16(r, k0, 1024)) = o;
  }
}
__global__ void pack_ae(const float* __restrict__ data, ushort_t* __restrict__ Ap) {
  int stride = gridDim.x * 256;
  for (int i = blockIdx.x * 256 + threadIdx.x; i < 11776 * 44; i += stride) {
    int m = i / 44, k0 = (i - m * 44) * 8;
    int b = m / TM1, t = m - b * TM1;
    const float* s = data + ((size_t)b * T_ + t) * OUT_;
    bf16x8 o;
    #pragma unroll
    for (int j = 0; j < 8; ++j) {
      int k = k0 + j;
      o[j] = (k < OUT_) ? f2b(s[k]) : (short)0;
    }
    *(bf16x8*)(Ap + pidx16(m, k0, 352)) = o;
  }
}
__global__ void pack_dc(const float* __restrict__ data, ushort_t* __restrict__ DCp,
                        float* __restrict__ DC) {
  int stride = gridDim.x * 256;
  for (int i = blockIdx.x * 256 + threadIdx.x; i < 512 * 44; i += stride) {
    int b = i / 44, k0 = (i - b * 44) * 8;
    const float* s = data + ((size_t)b * T_ + (T_ - 1)) * OUT_;
    bf16x8 o;
    #pragma unroll
    for (int j = 0; j < 8; ++j) {
      int k = k0 + j;
      float v = (k < OUT_) ? s[k] : 0.f;
      o[j] = f2b(v);
      if (k < OUT_) DC[(size_t)b * OUT_ + k] = v;
    }
    *(bf16x8*)(DCp + pidx16(b, k0, 352)) = o;
  }
}

extern "C" void kernel_launch(void* const* d_in, const int* in_sizes, int n_in,
                              void* d_out, int out_size, void* d_ws, size_t ws_size,
                              hipStream_t stream) {
  const float* data       = (const float*)d_in[0];
  const int*   timev      = (const int*)  d_in[1];
  const int*   weekday    = (const int*)  d_in[2];
  const float* w_data     = (const float*)d_in[3];
  const float* b_data     = (const float*)d_in[4];
  const float* time_table = (const float*)d_in[5];
  const float* day_table  = (const float*)d_in[6];
  const float* enc_Wih    = (const float*)d_in[7];
  const float* enc_Whh    = (const float*)d_in[8];
  const float* enc_bih    = (const float*)d_in[9];
  const float* enc_bhh    = (const float*)d_in[10];
  const float* dec_Wih    = (const float*)d_in[11];
  const float* dec_Whh    = (const float*)d_in[12];
  const float* dec_bih    = (const float*)d_in[13];
  const float* dec_bhh    = (const float*)d_in[14];
  const float* w_mlp      = (const float*)d_in[15];
  const float* b_mlp      = (const float*)d_in[16];
  float* out = (float*)d_out;

  char* base = (char*)d_ws;
  size_t o = 0;
  auto take = [&](size_t bytes) { void* p = base + o; o = (o + bytes + 511) & ~(size_t)511; return p; };
  const size_t WSZ = (size_t)6144 * 1024 * 2;
  ushort_t* Wih_e = (ushort_t*)take(WSZ);
  ushort_t* Whh_e = (ushort_t*)take(WSZ);
  ushort_t* Wih_d = (ushort_t*)take(WSZ);
  ushort_t* Whh_d = (ushort_t*)take(WSZ);
  ushort_t* WdTk  = (ushort_t*)take((size_t)384 * 1024 * 2);   // w_data rows-k packed
  ushort_t* WmT   = (ushort_t*)take((size_t)384 * 1024 * 2);
  ushort_t* CTpk  = (ushort_t*)take((size_t)320 * 1024 * 2);
  ushort_t* W0ep  = (ushort_t*)take((size_t)3072 * 352 * 2);
  ushort_t* W0dp  = (ushort_t*)take((size_t)3072 * 352 * 2);
  float*    CTe   = (float*)take((size_t)320 * 3072 * 4);
  float*    CTd   = (float*)take((size_t)320 * 3072 * 4);
  ushort_t* Ap    = (ushort_t*)take((size_t)11776 * 352 * 2);
  ushort_t* Xp    = (ushort_t*)take((size_t)23 * 512 * 1024 * 2);
  ushort_t* GXbuf = (ushort_t*)take((size_t)23 * 512 * 3072 * 2);
  ushort_t* GX0d  = (ushort_t*)take((size_t)512 * 3072 * 2);
  ushort_t* DCp   = (ushort_t*)take((size_t)512 * 352 * 2);
  float*    DC    = (float*)take((size_t)512 * OUT_ * 4);
  float*    Hfb   = (float*)take((size_t)4 * 512 * 1024 * 4 + (size_t)4 * 512 * 1024 * 2);
  if (o > ws_size) return; // ~187 MB required

  float* Hf[2][2]; ushort_t* Hp[2][2];
  ushort_t* Hpb = (ushort_t*)(Hfb + (size_t)4 * 512 * 1024);
  for (int l = 0; l < 2; ++l)
    for (int p = 0; p < 2; ++p) {
      Hf[l][p] = Hfb + (size_t)(l * 2 + p) * 512 * 1024;
      Hp[l][p] = Hpb + (size_t)(l * 2 + p) * 512 * 1024;
    }

  const size_t SLOT = (size_t)512 * 1024;
  const size_t WLAYER = (size_t)3072 * 1024;
  const size_t GXS = (size_t)512 * 3072;

  // ---- packs
  pack_k1024<<<3072, 256, 0, stream>>>(enc_Wih, Wih_e, 6144, 6144);
  pack_k1024<<<3072, 256, 0, stream>>>(enc_Whh, Whh_e, 6144, 6144);
  pack_k1024<<<3072, 256, 0, stream>>>(dec_Wih, Wih_d, 6144, 6144);
  pack_k1024<<<3072, 256, 0, stream>>>(dec_Whh, Whh_d, 6144, 6144);
  pack_k1024<<<192, 256, 0, stream>>>(w_data, WdTk, 384, OUT_);
  pack_wm<<<192, 256, 0, stream>>>(w_mlp, WmT);
  pack_ct<<<160, 256, 0, stream>>>(time_table, day_table, b_data, CTpk);
  pack_ae<<<2024, 256, 0, stream>>>(data, Ap);
  pack_dc<<<88, 256, 0, stream>>>(data, DCp, DC);

  // ---- combined-weight setup GEMMs
  gemm64<0><<<dim3(48, 6), 256, 0, stream>>>(Wih_e, WdTk, 32, nullptr, nullptr,
      nullptr, nullptr, 0, W0ep, nullptr, nullptr, nullptr);
  gemm64<0><<<dim3(48, 6), 256, 0, stream>>>(Wih_d, WdTk, 32, nullptr, nullptr,
      nullptr, nullptr, 0, W0dp, nullptr, nullptr, nullptr);
  gemm64<1><<<dim3(5, 48), 256, 0, stream>>>(CTpk, Wih_e, 32, nullptr, nullptr,
      nullptr, nullptr, 0, nullptr, CTe, nullptr, nullptr);
  gemm64<1><<<dim3(5, 48), 256, 0, stream>>>(CTpk, Wih_d, 32, nullptr, nullptr,
      nullptr, nullptr, 0, nullptr, CTd, nullptr, nullptr);

  // ---- encoder layer-0 gx (embed folded): all 23 timesteps
  gemm_gx0_enc<<<dim3(92, 24), 256, 0, stream>>>(Ap, W0ep, CTe, enc_bih,
      timev, weekday, GXbuf);

  // ---- zero initial hidden states
  hipMemsetAsync(Hf[0][0], 0, (size_t)512 * 1024 * 4, stream);
  hipMemsetAsync(Hf[1][0], 0, (size_t)512 * 1024 * 4, stream);
  hipMemsetAsync(Hp[0][0], 0, (size_t)512 * 1024 * 2, stream);
  hipMemsetAsync(Hp[1][0], 0, (size_t)512 * 1024 * 2, stream);

  int pl[2] = {0, 0};

  // ---- encoder layer-0 scan (writes Y0 into Xp slot t)
  for (int t = 0; t < TM1; ++t) {
    int p = pl[0];
    gru_hcell32<1><<<dim3(16, 32), 256, 0, stream>>>(
        Hp[0][p], Hf[0][p], Whh_e, enc_bhh,
        GXbuf + (size_t)t * GXS,
        Hf[0][1 - p], Hp[0][1 - p], Xp + (size_t)t * SLOT);
    pl[0] ^= 1;
  }

  // ---- encoder layer-1 gx (BK=64)
  gemm_gx1<<<dim3(92, 24), 256, 0, stream>>>(Xp, Wih_e + WLAYER, enc_bih + 3072, GXbuf);

  // ---- encoder layer-1 scan
  for (int t = 0; t < TM1; ++t) {
    int p = pl[1];
    gru_hcell32<0><<<dim3(16, 32), 256, 0, stream>>>(
        Hp[1][p], Hf[1][p], Whh_e + WLAYER, enc_bhh + 3072,
        GXbuf + (size_t)t * GXS,
        Hf[1][1 - p], Hp[1][1 - p], nullptr);
    pl[1] ^= 1;
  }

  // ---- decoder
  for (int s = 0; s < HORIZON_; ++s) {
    // gx0 = DC @ W0d' + tables + bih_d0  (embed folded)
    gemm64<2><<<dim3(8, 48), 256, 0, stream>>>(DCp, W0dp, 11, dec_bih, CTd,
        timev, weekday, s, GX0d, nullptr, nullptr, nullptr);
    int p0 = pl[0];
    gru_hcell32<0><<<dim3(16, 32), 256, 0, stream>>>(
        Hp[0][p0], Hf[0][p0], Whh_d, dec_bhh, GX0d,
        Hf[0][1 - p0], Hp[0][1 - p0], nullptr);
    pl[0] ^= 1; p0 = pl[0];
    int p1 = pl[1];
    gru_cell32<<<dim3(16, 32), 256, 0, stream>>>(
        Hp[0][p0], Hp[1][p1], Hf[1][p1],
        Wih_d + WLAYER, Whh_d + WLAYER, dec_bih + 3072, dec_bhh + 3072,
        Hf[1][1 - p1], Hp[1][1 - p1]);
    pl[1] ^= 1; p1 = pl[1];
    gemm64<3><<<dim3(8, 6), 256, 0, stream>>>(Hp[1][p1], WmT, 32, b_mlp, nullptr,
        nullptr, nullptr, s, nullptr, DC, out, DCp);
  }
}

// Round 5
// 1759.117 us; speedup vs baseline: 7.1408x; 1.1270x over previous
//
#include <hip/hip_runtime.h>
#include <math.h>

#define B_ 512
#define T_ 24
#define TM1 23
#define D_ 1024
#define OUT_ 325
#define HORIZON_ 12

typedef unsigned short ushort_t;
typedef __attribute__((ext_vector_type(8))) short bf16x8;
typedef __attribute__((ext_vector_type(4))) float f32x4;

#define MFMA16(a, b, c) __builtin_amdgcn_mfma_f32_16x16x32_bf16((a), (b), (c), 0, 0, 0)

__device__ __forceinline__ ushort_t f2b(float f) {
  union { float f; unsigned u; } v; v.f = f;
  unsigned r = (v.u + 0x7fffu + ((v.u >> 16) & 1u)) >> 16;
  return (ushort_t)r;
}
__device__ __forceinline__ float b2f(ushort_t s) {
  union { unsigned u; float f; } v; v.u = ((unsigned)s) << 16;
  return v.f;
}

// 16-row-granular packed fragment layout for (M x K) bf16, M%16==0, K%32==0.
// Segment (m>>4, k>>5) = 512 contiguous elems = one wave 1KB load.
// lane l, elem j <-> row m0+(l&15), col k0+(l>>4)*8+j
__device__ __forceinline__ size_t pidx16(int m, int k, int K) {
  return (((size_t)(m >> 4) * (K >> 5) + (k >> 5)) * 64
          + ((m & 15) + (((k >> 3) & 3) << 4))) * 8 + (k & 7);
}

#define GLOAD16(src, dst) \
  __builtin_amdgcn_global_load_lds((const __attribute__((address_space(1))) void*)(src), \
                                   (__attribute__((address_space(3))) void*)(dst), 16, 0, 0)

// =============== diagonal encoder step ===============
// z=0: layer-0 gh-only cell at t=k (gx precomputed in GXbuf, bih folded)
// z=1: layer-1 FULL cell at t=k-1 (gx from Y0p slot t, K=1024)
__global__ __launch_bounds__(256) void enc_diag(
    int k,
    const ushort_t* __restrict__ Hp0, const float* __restrict__ Hf0,
    float* __restrict__ Hf0o, ushort_t* __restrict__ Hp0o,
    const ushort_t* __restrict__ Whh0, const float* __restrict__ bhh0,
    const ushort_t* __restrict__ GXbuf, ushort_t* __restrict__ Y0p,
    const ushort_t* __restrict__ Hp1, const float* __restrict__ Hf1,
    float* __restrict__ Hf1o, ushort_t* __restrict__ Hp1o,
    const ushort_t* __restrict__ Wih1, const ushort_t* __restrict__ Whh1,
    const float* __restrict__ bih1, const float* __restrict__ bhh1)
{
  __shared__ ushort_t lds[2][16 * 512];
  const int tid = threadIdx.x, lane = tid & 63, w = tid >> 6;
  const int bx = blockIdx.x, by = blockIdx.y;
  const int wm = w >> 1, wn = w & 1;

  if (blockIdx.z == 0) {
    if (k >= TM1) return;
    const ushort_t* GXslot = GXbuf + (size_t)k * 512 * 3072;
    ushort_t* Seqp = Y0p + (size_t)k * 512 * 1024;
    f32x4 acc[3] = {};
    auto stage = [&](int buf, int kb) {
      #pragma unroll
      for (int r = 0; r < 2; ++r) {
        int s = w * 2 + r;
        const ushort_t* src;
        if (s < 2) src = Hp0 + ((size_t)(((bx * 32 + s * 16) >> 4) * 32 + kb)) * 512 + lane * 8;
        else { int g = (s - 2) >> 1, hf = (s - 2) & 1;
          src = Whh0 + ((size_t)(((g * 1024 + by * 32 + hf * 16) >> 4) * 32 + kb)) * 512 + lane * 8; }
        GLOAD16(src, &lds[buf][s * 512 + lane * 8]);
      }
    };
    stage(0, 0); __syncthreads();
    int cur = 0;
    for (int kb = 0; kb < 32; ++kb) {
      if (kb + 1 < 32) stage(cur ^ 1, kb + 1);
      const ushort_t* L = lds[cur];
      bf16x8 a = *(const bf16x8*)(L + wm * 512 + lane * 8);
      #pragma unroll
      for (int g = 0; g < 3; ++g) {
        bf16x8 b = *(const bf16x8*)(L + (2 + g * 2 + wn) * 512 + lane * 8);
        acc[g] = MFMA16(a, b, acc[g]);
      }
      __syncthreads(); cur ^= 1;
    }
    const int d = by * 32 + wn * 16 + (lane & 15);
    const float bh_r = bhh0[d], bh_z = bhh0[D_ + d], bh_n = bhh0[2 * D_ + d];
    #pragma unroll
    for (int q = 0; q < 4; ++q) {
      int m = bx * 32 + wm * 16 + ((lane >> 4) << 2) + q;
      const ushort_t* gxp = GXslot + (size_t)m * 3072 + d;
      float gx_r = b2f(gxp[0]), gx_z = b2f(gxp[D_]), gx_n = b2f(gxp[2 * D_]);
      float rr = 1.f / (1.f + __expf(-(gx_r + acc[0][q] + bh_r)));
      float zz = 1.f / (1.f + __expf(-(gx_z + acc[1][q] + bh_z)));
      float nn = tanhf(gx_n + rr * (acc[2][q] + bh_n));
      float h = Hf0[(size_t)m * D_ + d];
      float hnew = (1.f - zz) * nn + zz * h;
      Hf0o[(size_t)m * D_ + d] = hnew;
      ushort_t hb = f2b(hnew);
      size_t pi = pidx16(m, d, D_);
      Hp0o[pi] = hb; Seqp[pi] = hb;
    }
  } else {
    if (k < 1) return;
    const ushort_t* Xp_ = Y0p + (size_t)(k - 1) * 512 * 1024;
    f32x4 accx[3] = {}, acch[3] = {};
    auto stage = [&](int buf, int kb) {
      #pragma unroll
      for (int r = 0; r < 4; ++r) {
        int s = w * 4 + r;
        const ushort_t* src;
        if (s < 2) src = Xp_ + ((size_t)(((bx * 32 + s * 16) >> 4) * 32 + kb)) * 512 + lane * 8;
        else if (s < 4) src = Hp1 + ((size_t)(((bx * 32 + (s - 2) * 16) >> 4) * 32 + kb)) * 512 + lane * 8;
        else if (s < 10) { int g = (s - 4) >> 1, hf = (s - 4) & 1;
          src = Wih1 + ((size_t)(((g * 1024 + by * 32 + hf * 16) >> 4) * 32 + kb)) * 512 + lane * 8; }
        else { int g = (s - 10) >> 1, hf = (s - 10) & 1;
          src = Whh1 + ((size_t)(((g * 1024 + by * 32 + hf * 16) >> 4) * 32 + kb)) * 512 + lane * 8; }
        GLOAD16(src, &lds[buf][s * 512 + lane * 8]);
      }
    };
    stage(0, 0); __syncthreads();
    int cur = 0;
    for (int kb = 0; kb < 32; ++kb) {
      if (kb + 1 < 32) stage(cur ^ 1, kb + 1);
      const ushort_t* L = lds[cur];
      bf16x8 ax = *(const bf16x8*)(L + (0 + wm) * 512 + lane * 8);
      bf16x8 ah = *(const bf16x8*)(L + (2 + wm) * 512 + lane * 8);
      #pragma unroll
      for (int g = 0; g < 3; ++g) {
        bf16x8 bxw = *(const bf16x8*)(L + (4 + g * 2 + wn) * 512 + lane * 8);
        bf16x8 bhw = *(const bf16x8*)(L + (10 + g * 2 + wn) * 512 + lane * 8);
        accx[g] = MFMA16(ax, bxw, accx[g]);
        acch[g] = MFMA16(ah, bhw, acch[g]);
      }
      __syncthreads(); cur ^= 1;
    }
    const int d = by * 32 + wn * 16 + (lane & 15);
    const float bi_r = bih1[d], bi_z = bih1[D_ + d], bi_n = bih1[2 * D_ + d];
    const float bh_r = bhh1[d], bh_z = bhh1[D_ + d], bh_n = bhh1[2 * D_ + d];
    #pragma unroll
    for (int q = 0; q < 4; ++q) {
      int m = bx * 32 + wm * 16 + ((lane >> 4) << 2) + q;
      float rr = 1.f / (1.f + __expf(-(accx[0][q] + bi_r + acch[0][q] + bh_r)));
      float zz = 1.f / (1.f + __expf(-(accx[1][q] + bi_z + acch[1][q] + bh_z)));
      float nn = tanhf(accx[2][q] + bi_n + rr * (acch[2][q] + bh_n));
      float h = Hf1[(size_t)m * D_ + d];
      float hnew = (1.f - zz) * nn + zz * h;
      Hf1o[(size_t)m * D_ + d] = hnew;
      Hp1o[pidx16(m, d, D_)] = f2b(hnew);
    }
  }
}

// =============== decoder layer-0 cell: fused gx0 (K=352) + gh (K=1024) ===============
__global__ __launch_bounds__(256) void dec_cell0(
    const ushort_t* __restrict__ DCp, const ushort_t* __restrict__ Hp,
    const float* __restrict__ Hf,
    const ushort_t* __restrict__ W0dp,   // packed 3072x352 combined weight
    const ushort_t* __restrict__ Whh0,   // packed 3072x1024 (dec layer 0)
    const float* __restrict__ bhh0,
    const float* __restrict__ CTt,       // [288+][3072] time' rows (f32)
    const float* __restrict__ CBd,       // [512][3072] = day'+b_data'+bih0
    const int* __restrict__ timev, int step,
    float* __restrict__ Hf_out, ushort_t* __restrict__ Hp_out)
{
  __shared__ ushort_t lds[2][16 * 512];
  const int tid = threadIdx.x, lane = tid & 63, w = tid >> 6;
  const int bx = blockIdx.x, by = blockIdx.y;
  const int wm = w >> 1, wn = w & 1;
  f32x4 accx[3] = {}, acch[3] = {};

  auto stage_h = [&](int buf, int kb) {  // segs {2,3,10..15}
    #pragma unroll
    for (int r = 0; r < 2; ++r) {
      int s = (w == 0) ? (2 + r) : (8 + w * 2 + r);
      const ushort_t* src;
      if (s < 4) src = Hp + ((size_t)(((bx * 32 + (s - 2) * 16) >> 4) * 32 + kb)) * 512 + lane * 8;
      else { int g = (s - 10) >> 1, hf = (s - 10) & 1;
        src = Whh0 + ((size_t)(((g * 1024 + by * 32 + hf * 16) >> 4) * 32 + kb)) * 512 + lane * 8; }
      GLOAD16(src, &lds[buf][s * 512 + lane * 8]);
    }
  };
  auto stage_x = [&](int buf, int kb) {  // segs {0,1,4..9}, kb<11
    #pragma unroll
    for (int r = 0; r < 2; ++r) {
      int s = (w == 0) ? r : (2 + w * 2 + r);
      const ushort_t* src;
      if (s < 2) src = DCp + ((size_t)(((bx * 32 + s * 16) >> 4) * 11 + kb)) * 512 + lane * 8;
      else { int g = (s - 4) >> 1, hf = (s - 4) & 1;
        src = W0dp + ((size_t)(((g * 1024 + by * 32 + hf * 16) >> 4) * 11 + kb)) * 512 + lane * 8; }
      GLOAD16(src, &lds[buf][s * 512 + lane * 8]);
    }
  };

  stage_h(0, 0); stage_x(0, 0);
  __syncthreads();
  int cur = 0;
  for (int kb = 0; kb < 32; ++kb) {
    if (kb + 1 < 32) {
      stage_h(cur ^ 1, kb + 1);
      if (kb + 1 < 11) stage_x(cur ^ 1, kb + 1);
    }
    const ushort_t* L = lds[cur];
    bf16x8 ah = *(const bf16x8*)(L + (2 + wm) * 512 + lane * 8);
    if (kb < 11) {
      bf16x8 ax = *(const bf16x8*)(L + (0 + wm) * 512 + lane * 8);
      #pragma unroll
      for (int g = 0; g < 3; ++g) {
        bf16x8 bxw = *(const bf16x8*)(L + (4 + g * 2 + wn) * 512 + lane * 8);
        accx[g] = MFMA16(ax, bxw, accx[g]);
      }
    }
    #pragma unroll
    for (int g = 0; g < 3; ++g) {
      bf16x8 bhw = *(const bf16x8*)(L + (10 + g * 2 + wn) * 512 + lane * 8);
      acch[g] = MFMA16(ah, bhw, acch[g]);
    }
    __syncthreads(); cur ^= 1;
  }

  const int d = by * 32 + wn * 16 + (lane & 15);
  const float bh_r = bhh0[d], bh_z = bhh0[D_ + d], bh_n = bhh0[2 * D_ + d];
  #pragma unroll
  for (int q = 0; q < 4; ++q) {
    int m = bx * 32 + wm * 16 + ((lane >> 4) << 2) + q;
    int ti = (timev[m * T_ + (T_ - 1)] + step) % 288;
    const float* ctt = CTt + (size_t)ti * 3072;
    const float* cb  = CBd + (size_t)m * 3072;
    float gx_r = accx[0][q] + ctt[d] + cb[d];
    float gx_z = accx[1][q] + ctt[D_ + d] + cb[D_ + d];
    float gx_n = accx[2][q] + ctt[2 * D_ + d] + cb[2 * D_ + d];
    float rr = 1.f / (1.f + __expf(-(gx_r + acch[0][q] + bh_r)));
    float zz = 1.f / (1.f + __expf(-(gx_z + acch[1][q] + bh_z)));
    float nn = tanhf(gx_n + rr * (acch[2][q] + bh_n));
    float h = Hf[(size_t)m * D_ + d];
    float hnew = (1.f - zz) * nn + zz * h;
    Hf_out[(size_t)m * D_ + d] = hnew;
    Hp_out[pidx16(m, d, D_)] = f2b(hnew);
  }
}

// =============== decoder layer-1 full cell (K=1024 + K=1024) ===============
__global__ __launch_bounds__(256) void gru_cell32(
    const ushort_t* __restrict__ Xp_, const ushort_t* __restrict__ Hp,
    const float* __restrict__ Hf,
    const ushort_t* __restrict__ Wih_l, const ushort_t* __restrict__ Whh_l,
    const float* __restrict__ bih_l, const float* __restrict__ bhh_l,
    float* __restrict__ Hf_out, ushort_t* __restrict__ Hp_out)
{
  __shared__ ushort_t lds[2][16 * 512];
  const int tid = threadIdx.x, lane = tid & 63, w = tid >> 6;
  const int bx = blockIdx.x, by = blockIdx.y;
  const int wm = w >> 1, wn = w & 1;
  f32x4 accx[3] = {}, acch[3] = {};

  auto stage = [&](int buf, int kb) {
    #pragma unroll
    for (int r = 0; r < 4; ++r) {
      int s = w * 4 + r;
      const ushort_t* src;
      if (s < 2) src = Xp_ + ((size_t)(((bx * 32 + s * 16) >> 4) * 32 + kb)) * 512 + lane * 8;
      else if (s < 4) src = Hp + ((size_t)(((bx * 32 + (s - 2) * 16) >> 4) * 32 + kb)) * 512 + lane * 8;
      else if (s < 10) { int g = (s - 4) >> 1, hf = (s - 4) & 1;
        src = Wih_l + ((size_t)(((g * 1024 + by * 32 + hf * 16) >> 4) * 32 + kb)) * 512 + lane * 8; }
      else { int g = (s - 10) >> 1, hf = (s - 10) & 1;
        src = Whh_l + ((size_t)(((g * 1024 + by * 32 + hf * 16) >> 4) * 32 + kb)) * 512 + lane * 8; }
      GLOAD16(src, &lds[buf][s * 512 + lane * 8]);
    }
  };

  stage(0, 0); __syncthreads();
  int cur = 0;
  for (int kb = 0; kb < 32; ++kb) {
    if (kb + 1 < 32) stage(cur ^ 1, kb + 1);
    const ushort_t* L = lds[cur];
    bf16x8 ax = *(const bf16x8*)(L + (0 + wm) * 512 + lane * 8);
    bf16x8 ah = *(const bf16x8*)(L + (2 + wm) * 512 + lane * 8);
    #pragma unroll
    for (int g = 0; g < 3; ++g) {
      bf16x8 bxw = *(const bf16x8*)(L + (4 + g * 2 + wn) * 512 + lane * 8);
      bf16x8 bhw = *(const bf16x8*)(L + (10 + g * 2 + wn) * 512 + lane * 8);
      accx[g] = MFMA16(ax, bxw, accx[g]);
      acch[g] = MFMA16(ah, bhw, acch[g]);
    }
    __syncthreads(); cur ^= 1;
  }

  const int d = by * 32 + wn * 16 + (lane & 15);
  const float bi_r = bih_l[d], bi_z = bih_l[D_ + d], bi_n = bih_l[2 * D_ + d];
  const float bh_r = bhh_l[d], bh_z = bhh_l[D_ + d], bh_n = bhh_l[2 * D_ + d];
  #pragma unroll
  for (int q = 0; q < 4; ++q) {
    int m = bx * 32 + wm * 16 + ((lane >> 4) << 2) + q;
    float rr = 1.f / (1.f + __expf(-(accx[0][q] + bi_r + acch[0][q] + bh_r)));
    float zz = 1.f / (1.f + __expf(-(accx[1][q] + bi_z + acch[1][q] + bh_z)));
    float nn = tanhf(accx[2][q] + bi_n + rr * (acch[2][q] + bh_n));
    float h = Hf[(size_t)m * D_ + d];
    float hnew = (1.f - zz) * nn + zz * h;
    Hf_out[(size_t)m * D_ + d] = hnew;
    Hp_out[pidx16(m, d, D_)] = f2b(hnew);
  }
}

// =============== encoder layer-0 gx via combined weights: 128-tile, K=352 ===============
__global__ __launch_bounds__(256) void gemm_gx0_enc(
    const ushort_t* __restrict__ Ap,   // packed 11776x352 (data)
    const ushort_t* __restrict__ W0p,  // packed 3072x352 (combined)
    const float* __restrict__ CTt,     // [288+][3072] time'
    const float* __restrict__ CBe,     // [512][3072] day'+b_data'+bih0
    const int* __restrict__ timev,
    ushort_t* __restrict__ GX)         // [23*512][3072] bf16 (slot t, row b)
{
  __shared__ ushort_t lds[2][16 * 512];
  const int tid = threadIdx.x, lane = tid & 63, w = tid >> 6;
  const int bx = blockIdx.x, by = blockIdx.y;
  const int wm = w >> 1, wn = w & 1;
  f32x4 acc[4][4] = {};

  auto stage = [&](int buf, int kb) {
    #pragma unroll
    for (int r = 0; r < 4; ++r) {
      int s = r * 4 + w;
      const ushort_t* src = (s < 8)
          ? Ap  + ((size_t)(((bx * 128 + s * 16) >> 4) * 11 + kb)) * 512 + lane * 8
          : W0p + ((size_t)(((by * 128 + (s - 8) * 16) >> 4) * 11 + kb)) * 512 + lane * 8;
      GLOAD16(src, &lds[buf][s * 512 + lane * 8]);
    }
  };

  stage(0, 0); __syncthreads();
  int cur = 0;
  for (int kb = 0; kb < 11; ++kb) {
    if (kb + 1 < 11) stage(cur ^ 1, kb + 1);
    const ushort_t* L = lds[cur];
    bf16x8 af[4], bf[4];
    #pragma unroll
    for (int f = 0; f < 4; ++f) {
      af[f] = *(const bf16x8*)(L + (wm * 4 + f) * 512 + lane * 8);
      bf[f] = *(const bf16x8*)(L + (8 + wn * 4 + f) * 512 + lane * 8);
    }
    #pragma unroll
    for (int fm = 0; fm < 4; ++fm)
      #pragma unroll
      for (int fn = 0; fn < 4; ++fn)
        acc[fm][fn] = MFMA16(af[fm], bf[fn], acc[fm][fn]);
    __syncthreads(); cur ^= 1;
  }

  #pragma unroll
  for (int fm = 0; fm < 4; ++fm) {
    #pragma unroll
    for (int q = 0; q < 4; ++q) {
      int m = bx * 128 + wm * 64 + fm * 16 + ((lane >> 4) << 2) + q;
      int b = m / 23, t = m - b * 23;
      int ti = timev[b * T_ + t] % 288;
      const float* ctt = CTt + (size_t)ti * 3072;
      const float* cb  = CBe + (size_t)b * 3072;
      #pragma unroll
      for (int fn = 0; fn < 4; ++fn) {
        int n = by * 128 + wn * 64 + fn * 16 + (lane & 15);
        float v = acc[fm][fn][q] + ctt[n] + cb[n];
        GX[((size_t)t * 512 + b) * 3072 + n] = f2b(v);
      }
    }
  }
}

// =============== generic 64-tile GEMM with epilogues ===============
// EPI 0: combined-weight setup -> outp[pidx16(m,n,352)], n<352
// EPI 1: CT' setup             -> outf[m*3072+n] (f32)
// EPI 3: mlp head              -> n<325: v=acc+bias[n]+DC; dout, DC, DCp
template<int EPI>
__global__ __launch_bounds__(256) void gemm64(
    const ushort_t* __restrict__ Ap, const ushort_t* __restrict__ Wp, int K32,
    const float* __restrict__ bias, int step,
    ushort_t* __restrict__ outp, float* __restrict__ outf,
    float* __restrict__ dout, ushort_t* __restrict__ DCp)
{
  __shared__ ushort_t lds[2][8 * 512];
  const int tid = threadIdx.x, lane = tid & 63, w = tid >> 6;
  const int bx = blockIdx.x, by = blockIdx.y;
  const int wm = w >> 1, wn = w & 1;
  f32x4 acc[2][2] = {};

  auto stage = [&](int buf, int kb) {
    #pragma unroll
    for (int r = 0; r < 2; ++r) {
      int s = r * 4 + w;
      const ushort_t* src = (s < 4)
          ? Ap + ((size_t)(((bx * 64 + s * 16) >> 4) * K32 + kb)) * 512 + lane * 8
          : Wp + ((size_t)(((by * 64 + (s - 4) * 16) >> 4) * K32 + kb)) * 512 + lane * 8;
      GLOAD16(src, &lds[buf][s * 512 + lane * 8]);
    }
  };

  stage(0, 0); __syncthreads();
  int cur = 0;
  for (int kb = 0; kb < K32; ++kb) {
    if (kb + 1 < K32) stage(cur ^ 1, kb + 1);
    const ushort_t* L = lds[cur];
    bf16x8 af[2], bf[2];
    #pragma unroll
    for (int f = 0; f < 2; ++f) {
      af[f] = *(const bf16x8*)(L + (wm * 2 + f) * 512 + lane * 8);
      bf[f] = *(const bf16x8*)(L + (4 + wn * 2 + f) * 512 + lane * 8);
    }
    #pragma unroll
    for (int fm = 0; fm < 2; ++fm)
      #pragma unroll
      for (int fn = 0; fn < 2; ++fn)
        acc[fm][fn] = MFMA16(af[fm], bf[fn], acc[fm][fn]);
    __syncthreads(); cur ^= 1;
  }

  #pragma unroll
  for (int fm = 0; fm < 2; ++fm) {
    #pragma unroll
    for (int q = 0; q < 4; ++q) {
      int m = bx * 64 + wm * 32 + fm * 16 + ((lane >> 4) << 2) + q;
      #pragma unroll
      for (int fn = 0; fn < 2; ++fn) {
        int n = by * 64 + wn * 32 + fn * 16 + (lane & 15);
        float v = acc[fm][fn][q];
        if (EPI == 0) {
          if (n < 352) outp[pidx16(m, n, 352)] = f2b(v);
        } else if (EPI == 1) {
          outf[(size_t)m * 3072 + n] = v;
        } else {
          if (n < OUT_) {
            v += bias[n] + outf[(size_t)m * OUT_ + n];
            dout[((size_t)m * HORIZON_ + step) * OUT_ + n] = v;
            outf[(size_t)m * OUT_ + n] = v;
            DCp[pidx16(m, n, 352)] = f2b(v);
          }
        }
      }
    }
  }
}

// =============== CB = day' + b_data' + bih (per batch row) ===============
__global__ void build_cb(const float* __restrict__ CT, const float* __restrict__ bih0,
                         const int* __restrict__ weekday, float* __restrict__ CB)
{
  int idx = blockIdx.x * 256 + threadIdx.x;
  if (idx >= 512 * 3072) return;
  int b = idx / 3072, n = idx - b * 3072;
  CB[idx] = CT[(size_t)(288 + weekday[b]) * 3072 + n] + CT[(size_t)295 * 3072 + n] + bih0[n];
}

// ================= dest-major pack kernels (coalesced 16B writes) =================
__global__ void pack_k1024(const float* __restrict__ src, ushort_t* __restrict__ dst,
                           int total, int Mvalid) {
  int stride = gridDim.x * 256;
  for (int i = blockIdx.x * 256 + threadIdx.x; i < total; i += stride) {
    int seg = i >> 6, q = i & 63;
    int m = (seg >> 5) * 16 + (q & 15);
    int k = (seg & 31) * 32 + (q >> 4) * 8;
    bf16x8 o;
    if (m < Mvalid) {
      const float* s = src + (size_t)m * 1024 + k;
      float4 v0 = *(const float4*)s, v1 = *(const float4*)(s + 4);
      o[0] = f2b(v0.x); o[1] = f2b(v0.y); o[2] = f2b(v0.z); o[3] = f2b(v0.w);
      o[4] = f2b(v1.x); o[5] = f2b(v1.y); o[6] = f2b(v1.z); o[7] = f2b(v1.w);
    } else o = bf16x8{0,0,0,0,0,0,0,0};
    *(bf16x8*)(dst + (size_t)i * 8) = o;
  }
}
__global__ void pack_wm(const float* __restrict__ w_mlp, ushort_t* __restrict__ dst) {
  int stride = gridDim.x * 256;
  for (int i = blockIdx.x * 256 + threadIdx.x; i < 384 * 128; i += stride) {
    int seg = i >> 6, q = i & 63;
    int n = (seg >> 5) * 16 + (q & 15);
    int k = (seg & 31) * 32 + (q >> 4) * 8;
    bf16x8 o;
    #pragma unroll
    for (int j = 0; j < 8; ++j)
      o[j] = (n < OUT_) ? f2b(w_mlp[(size_t)(k + j) * OUT_ + n]) : (short)0;
    *(bf16x8*)(dst + (size_t)i * 8) = o;
  }
}
__global__ void pack_ct(const float* __restrict__ time_table, const float* __restrict__ day_table,
                        const float* __restrict__ b_data, ushort_t* __restrict__ dst) {
  int stride = gridDim.x * 256;
  for (int i = blockIdx.x * 256 + threadIdx.x; i < 320 * 128; i += stride) {
    int seg = i >> 6, q = i & 63;
    int r = (seg >> 5) * 16 + (q & 15);
    int k = (seg & 31) * 32 + (q >> 4) * 8;
    const float* s = nullptr;
    if (r < 288) s = time_table + (size_t)r * 1024 + k;
    else if (r < 295) s = day_table + (size_t)(r - 288) * 1024 + k;
    else if (r == 295) s = b_data + k;
    bf16x8 o;
    #pragma unroll
    for (int j = 0; j < 8; ++j) o[j] = s ? f2b(s[j]) : (short)0;
    *(bf16x8*)(dst + (size_t)i * 8) = o;
  }
}
__global__ void pack_ae(const float* __restrict__ data, ushort_t* __restrict__ Ap) {
  int stride = gridDim.x * 256;
  const int total = (11776 / 16) * 11 * 64;
  for (int i = blockIdx.x * 256 + threadIdx.x; i < total; i += stride) {
    int seg = i >> 6, q = i & 63;
    int m = (seg / 11) * 16 + (q & 15);
    int k = (seg % 11) * 32 + (q >> 4) * 8;
    int b = m / TM1, t = m - b * TM1;
    const float* s = data + ((size_t)b * T_ + t) * OUT_;
    bf16x8 o;
    #pragma unroll
    for (int j = 0; j < 8; ++j) {
      int kk = k + j;
      o[j] = (kk < OUT_) ? f2b(s[kk]) : (short)0;
    }
    *(bf16x8*)(Ap + (size_t)i * 8) = o;
  }
}
__global__ void pack_dc(const float* __restrict__ data, ushort_t* __restrict__ DCp,
                        float* __restrict__ DC) {
  int stride = gridDim.x * 256;
  const int total = (512 / 16) * 11 * 64;
  for (int i = blockIdx.x * 256 + threadIdx.x; i < total; i += stride) {
    int seg = i >> 6, q = i & 63;
    int b = (seg / 11) * 16 + (q & 15);
    int k = (seg % 11) * 32 + (q >> 4) * 8;
    const float* s = data + ((size_t)b * T_ + (T_ - 1)) * OUT_;
    bf16x8 o;
    #pragma unroll
    for (int j = 0; j < 8; ++j) {
      int kk = k + j;
      float v = (kk < OUT_) ? s[kk] : 0.f;
      o[j] = f2b(v);
      if (kk < OUT_) DC[(size_t)b * OUT_ + kk] = v;
    }
    *(bf16x8*)(DCp + (size_t)i * 8) = o;
  }
}

extern "C" void kernel_launch(void* const* d_in, const int* in_sizes, int n_in,
                              void* d_out, int out_size, void* d_ws, size_t ws_size,
                              hipStream_t stream) {
  const float* data       = (const float*)d_in[0];
  const int*   timev      = (const int*)  d_in[1];
  const int*   weekday    = (const int*)  d_in[2];
  const float* w_data     = (const float*)d_in[3];
  const float* b_data     = (const float*)d_in[4];
  const float* time_table = (const float*)d_in[5];
  const float* day_table  = (const float*)d_in[6];
  const float* enc_Wih    = (const float*)d_in[7];
  const float* enc_Whh    = (const float*)d_in[8];
  const float* enc_bih    = (const float*)d_in[9];
  const float* enc_bhh    = (const float*)d_in[10];
  const float* dec_Wih    = (const float*)d_in[11];
  const float* dec_Whh    = (const float*)d_in[12];
  const float* dec_bih    = (const float*)d_in[13];
  const float* dec_bhh    = (const float*)d_in[14];
  const float* w_mlp      = (const float*)d_in[15];
  const float* b_mlp      = (const float*)d_in[16];
  float* out = (float*)d_out;

  char* base = (char*)d_ws;
  size_t o = 0;
  auto take = [&](size_t bytes) { void* p = base + o; o = (o + bytes + 511) & ~(size_t)511; return p; };
  const size_t WSZ = (size_t)6144 * 1024 * 2;
  ushort_t* Wih_e = (ushort_t*)take(WSZ);
  ushort_t* Whh_e = (ushort_t*)take(WSZ);
  ushort_t* Wih_d = (ushort_t*)take(WSZ);
  ushort_t* Whh_d = (ushort_t*)take(WSZ);
  ushort_t* WdTk  = (ushort_t*)take((size_t)384 * 1024 * 2);
  ushort_t* WmT   = (ushort_t*)take((size_t)384 * 1024 * 2);
  ushort_t* CTpk  = (ushort_t*)take((size_t)320 * 1024 * 2);
  ushort_t* W0ep  = (ushort_t*)take((size_t)3072 * 352 * 2);
  ushort_t* W0dp  = (ushort_t*)take((size_t)3072 * 352 * 2);
  float*    CTe   = (float*)take((size_t)320 * 3072 * 4);
  float*    CTd   = (float*)take((size_t)320 * 3072 * 4);
  float*    CBe   = (float*)take((size_t)512 * 3072 * 4);
  float*    CBd   = (float*)take((size_t)512 * 3072 * 4);
  ushort_t* Ap    = (ushort_t*)take((size_t)11776 * 352 * 2);
  ushort_t* Xp    = (ushort_t*)take((size_t)23 * 512 * 1024 * 2);
  ushort_t* GXbuf = (ushort_t*)take((size_t)23 * 512 * 3072 * 2);
  ushort_t* DCp   = (ushort_t*)take((size_t)512 * 352 * 2);
  float*    DC    = (float*)take((size_t)512 * OUT_ * 4);
  float*    Hfb   = (float*)take((size_t)4 * 512 * 1024 * 4 + (size_t)4 * 512 * 1024 * 2);
  if (o > ws_size) return; // ~200 MB required

  float* Hf0[2], *Hf1[2]; ushort_t* Hp0[2], *Hp1[2];
  ushort_t* Hpb = (ushort_t*)(Hfb + (size_t)4 * 512 * 1024);
  for (int p = 0; p < 2; ++p) {
    Hf0[p] = Hfb + (size_t)p * 512 * 1024;
    Hf1[p] = Hfb + (size_t)(2 + p) * 512 * 1024;
    Hp0[p] = Hpb + (size_t)p * 512 * 1024;
    Hp1[p] = Hpb + (size_t)(2 + p) * 512 * 1024;
  }

  const size_t SLOT = (size_t)512 * 1024;
  const size_t WLAYER = (size_t)3072 * 1024;

  // ---- packs (dest-major, coalesced writes)
  pack_k1024<<<3072, 256, 0, stream>>>(enc_Wih, Wih_e, 6144 * 128, 6144);
  pack_k1024<<<3072, 256, 0, stream>>>(enc_Whh, Whh_e, 6144 * 128, 6144);
  pack_k1024<<<3072, 256, 0, stream>>>(dec_Wih, Wih_d, 6144 * 128, 6144);
  pack_k1024<<<3072, 256, 0, stream>>>(dec_Whh, Whh_d, 6144 * 128, 6144);
  pack_k1024<<<192, 256, 0, stream>>>(w_data, WdTk, 384 * 128, OUT_);
  pack_wm<<<192, 256, 0, stream>>>(w_mlp, WmT);
  pack_ct<<<160, 256, 0, stream>>>(time_table, day_table, b_data, CTpk);
  pack_ae<<<2048, 256, 0, stream>>>(data, Ap);
  pack_dc<<<88, 256, 0, stream>>>(data, DCp, DC);

  // ---- combined-weight setup GEMMs
  gemm64<0><<<dim3(48, 6), 256, 0, stream>>>(Wih_e, WdTk, 32, nullptr, 0, W0ep, nullptr, nullptr, nullptr);
  gemm64<0><<<dim3(48, 6), 256, 0, stream>>>(Wih_d, WdTk, 32, nullptr, 0, W0dp, nullptr, nullptr, nullptr);
  gemm64<1><<<dim3(5, 48), 256, 0, stream>>>(CTpk, Wih_e, 32, nullptr, 0, nullptr, CTe, nullptr, nullptr);
  gemm64<1><<<dim3(5, 48), 256, 0, stream>>>(CTpk, Wih_d, 32, nullptr, 0, nullptr, CTd, nullptr, nullptr);
  build_cb<<<6144, 256, 0, stream>>>(CTe, enc_bih, weekday, CBe);
  build_cb<<<6144, 256, 0, stream>>>(CTd, dec_bih, weekday, CBd);

  // ---- encoder layer-0 gx (embed folded): all 23 timesteps
  gemm_gx0_enc<<<dim3(92, 24), 256, 0, stream>>>(Ap, W0ep, CTe, CBe, timev, GXbuf);

  // ---- zero initial hidden states
  hipMemsetAsync(Hf0[0], 0, (size_t)512 * 1024 * 4, stream);
  hipMemsetAsync(Hf1[0], 0, (size_t)512 * 1024 * 4, stream);
  hipMemsetAsync(Hp0[0], 0, (size_t)512 * 1024 * 2, stream);
  hipMemsetAsync(Hp1[0], 0, (size_t)512 * 1024 * 2, stream);

  // ---- diagonal encoder: k=0..23; z=0 -> layer0 t=k, z=1 -> layer1 t=k-1
  int p0 = 0, p1 = 0;
  for (int k = 0; k <= TM1; ++k) {
    enc_diag<<<dim3(16, 32, 2), 256, 0, stream>>>(k,
        Hp0[p0], Hf0[p0], Hf0[1 - p0], Hp0[1 - p0], Whh_e, enc_bhh, GXbuf, Xp,
        Hp1[p1], Hf1[p1], Hf1[1 - p1], Hp1[1 - p1],
        Wih_e + WLAYER, Whh_e + WLAYER, enc_bih + 3072, enc_bhh + 3072);
    if (k < TM1) p0 ^= 1;
    if (k >= 1)  p1 ^= 1;
  }

  // ---- decoder: 3 kernels per step
  for (int s = 0; s < HORIZON_; ++s) {
    dec_cell0<<<dim3(16, 32), 256, 0, stream>>>(
        DCp, Hp0[p0], Hf0[p0], W0dp, Whh_d, dec_bhh, CTd, CBd, timev, s,
        Hf0[1 - p0], Hp0[1 - p0]);
    p0 ^= 1;
    gru_cell32<<<dim3(16, 32), 256, 0, stream>>>(
        Hp0[p0], Hp1[p1], Hf1[p1],
        Wih_d + WLAYER, Whh_d + WLAYER, dec_bih + 3072, dec_bhh + 3072,
        Hf1[1 - p1], Hp1[1 - p1]);
    p1 ^= 1;
    gemm64<3><<<dim3(8, 6), 256, 0, stream>>>(
        Hp1[p1], WmT, 32, b_mlp, s, nullptr, DC, out, DCp);
  }
}